// Round 2
// baseline (515.372 us; speedup 1.0000x reference)
//
#include <hip/hip_runtime.h>
#include <hip/hip_bf16.h>
#include <stdint.h>

// Problem constants
#define BB 4
#define TT 2048
#define CC 2048
#define HH 16
#define DD 128
#define MM (BB*TT)   // 8192 rows

typedef __attribute__((ext_vector_type(8))) short bh8;   // 8 bf16 (4 VGPRs)
typedef __attribute__((ext_vector_type(4))) float fx4;   // MFMA 16x16 accumulator

__device__ inline ushort f2bf(float x) {
    union { float f; uint32_t u; } c; c.f = x;
    uint32_t lsb = (c.u >> 16) & 1u;
    return (ushort)((c.u + 0x7fffu + lsb) >> 16);
}

__device__ inline void async16(const void* g, void* l) {
    __builtin_amdgcn_global_load_lds(
        (const __attribute__((address_space(1))) uint32_t*)g,
        (__attribute__((address_space(3))) uint32_t*)l, 16, 0, 0);
}

// ---------------------------------------------------------------------------
// Fused fp32 -> bf16 convert for all 3 inputs (blockIdx.y selects tensor)
// ---------------------------------------------------------------------------
__global__ __launch_bounds__(256) void convert3_k(
    const float* __restrict__ i0, const float* __restrict__ i1,
    const float* __restrict__ i2,
    ushort* __restrict__ o0, ushort* __restrict__ o1, ushort* __restrict__ o2,
    int n)
{
    const float* in; ushort* out;
    switch (blockIdx.y) {
        case 0:  in = i0; out = o0; break;
        case 1:  in = i1; out = o1; break;
        default: in = i2; out = o2; break;
    }
    int i = (int)(blockIdx.x * 256 + threadIdx.x) * 4;
    if (i + 3 < n) {
        float4 v = *(const float4*)&in[i];
        ushort4 o;
        o.x = f2bf(v.x); o.y = f2bf(v.y); o.z = f2bf(v.z); o.w = f2bf(v.w);
        *(ushort4*)&out[i] = o;
    }
}

// ---------------------------------------------------------------------------
// Fused weight transpose+convert for all 4 weights (blockIdx.z selects).
// W[k][n] fp32 -> Wt[n][k] bf16 (CC x CC), ushort2 stores.
// ---------------------------------------------------------------------------
__global__ __launch_bounds__(256) void transpose4_w_k(
    const float* __restrict__ w0, const float* __restrict__ w1,
    const float* __restrict__ w2, const float* __restrict__ w3,
    ushort* __restrict__ t0, ushort* __restrict__ t1,
    ushort* __restrict__ t2, ushort* __restrict__ t3)
{
    const float* W; ushort* Wt;
    switch (blockIdx.z) {
        case 0:  W = w0; Wt = t0; break;
        case 1:  W = w1; Wt = t1; break;
        case 2:  W = w2; Wt = t2; break;
        default: W = w3; Wt = t3; break;
    }
    __shared__ __align__(16) ushort tile[32][33];
    const int n0 = blockIdx.x * 32, k0 = blockIdx.y * 32;
    const int tx = threadIdx.x, ty = threadIdx.y;   // (32, 8)
#pragma unroll
    for (int r = 0; r < 32; r += 8)
        tile[ty + r][tx] = f2bf(W[(size_t)(k0 + ty + r) * CC + n0 + tx]);  // [kl][nl]
    __syncthreads();
    const int tid = ty * 32 + tx;
    const int p = tid & 15;        // k-pair index
    const int row = tid >> 4;      // 0..15
#pragma unroll
    for (int rr = 0; rr < 2; ++rr) {
        const int n_row = row + rr * 16;
        ushort2 w2;
        w2.x = tile[2 * p][n_row];
        w2.y = tile[2 * p + 1][n_row];
        *(ushort2*)&Wt[(size_t)(n0 + n_row) * CC + k0 + 2 * p] = w2;
    }
}

// ---------------------------------------------------------------------------
// V transpose per head: V[b,t,h*D+d] bf16 -> Vt[((b*H+h)*D+d)*T + pnew(t)]
// pnew: within each 32-aligned t-block, with t = jj*16 + fg*4 + r:
//   p = fg*8 + jj*4 + r.
// This is the PV A-fragment k-slot order of the SWAPPED-QK^T register
// softmax: lane (fr,fg) holds P[q][kv = jj*16+fg*4+r] and feeds MFMA
// k-index fg*8+jj*4+r, so V rows must be permuted identically.
// ---------------------------------------------------------------------------
__global__ __launch_bounds__(256) void transpose_v_k(
    const ushort* __restrict__ V, ushort* __restrict__ Vt)
{
    __shared__ __align__(16) ushort tile[32][33];
    const int bh = blockIdx.z;
    const int b = bh >> 4, h = bh & 15;
    const int t0 = blockIdx.y * 32, d0 = blockIdx.x * 32;
    const int tx = threadIdx.x, ty = threadIdx.y;   // (32, 8)
    const ushort* Vp = V + (size_t)b * TT * CC + h * DD;
#pragma unroll
    for (int r = 0; r < 32; r += 8)
        tile[ty + r][tx] = Vp[(size_t)(t0 + ty + r) * CC + d0 + tx];  // [t][d]
    __syncthreads();
    ushort* Vtp = Vt + (size_t)bh * DD * TT;
    const int tt = t0 + tx;
    const int pnew = (tt & ~31) | (((tt >> 2) & 3) << 3) | (((tt >> 4) & 1) << 2) | (tt & 3);
#pragma unroll
    for (int r = 0; r < 32; r += 8)
        Vtp[(size_t)(d0 + ty + r) * TT + pnew] = tile[tx][ty + r];
}

// ---------------------------------------------------------------------------
// GEMM v8: m201-template port with K-HALF granularity. UNCHANGED.
// ---------------------------------------------------------------------------
template<int OUTF>
__global__ __launch_bounds__(512, 2) void gemm_bf16_k(
    const ushort* __restrict__ A, const ushort* __restrict__ Bt,
    const float* __restrict__ bias, void* __restrict__ Cv, float osc)
{
    __shared__ __align__(16) char Gsm[2][65536];  // [dbuf][A.k0|A.k1|B.k0|B.k1]

    const int tid = (int)threadIdx.x;
    const int lane = tid & 63, wave = tid >> 6;
    const int fr = lane & 15, fg = lane >> 4;      // frag row / k-slot group
    const int wm = wave >> 2, wn = wave & 3;       // 2m x 4n wave grid

    const int n_tile = (int)blockIdx.x & 7;        // XCD-pinned B panel
    const int m_tile = (int)blockIdx.x >> 3;
    const int m0 = m_tile * 256, n0 = n_tile * 256;

    const ushort* Ag = A  + (size_t)m0 * CC;
    const ushort* Bg = Bt + (size_t)n0 * CC;
    const int nt = CC / 64;                        // 32 K-tiles (BK=64)

    // stage group g of tile t: g0=A.k0 g1=B.k0 g2=A.k1 g3=B.k1 (2 loads)
    auto STAGE_G = [&](int t, int g) {
        if (t >= nt) return;
        const int khalf = g >> 1, isB = g & 1;
        char* base = Gsm[t & 1] + isB * 32768 + khalf * 16384;
        const ushort* src = isB ? Bg : Ag;
        const int kbase = t * 64 + khalf * 32;
#pragma unroll
        for (int l = 0; l < 2; ++l) {
            const int u = l * 512 + tid;
            const int j = u >> 3, s = u & 7;
            const int ek = s ^ (j & 7);
            const int e = (ek >> 2) & 1, ks = ek & 3;
            async16(src + (size_t)(2 * j + e) * CC + kbase + ks * 8,
                    base + u * 16);
        }
    };

    // fragment byte offsets within a 16KB region (pair-XOR; +16 rows = +1024)
    const int slot = ((((fr & 1) << 2) | fg) ^ ((fr >> 1) & 7));
    const int offA = (wm * 64 + (fr >> 1)) * 128 + slot * 16;           // +mf*1024
    const int offB = 32768 + (wn * 32 + (fr >> 1)) * 128 + slot * 16;   // +nf*1024

    fx4 acc[8][4];
#pragma unroll
    for (int i = 0; i < 8; ++i)
#pragma unroll
        for (int j = 0; j < 4; ++j)
            acc[i][j] = (fx4){0.f, 0.f, 0.f, 0.f};

    // prologue: tile 0 all 4 groups (8 loads/thread)
#pragma unroll
    for (int g = 0; g < 4; ++g) STAGE_G(0, g);

#pragma unroll 1
    for (int t = 0; t < nt; ++t) {
        const char* kb = Gsm[t & 1];
#pragma unroll
        for (int kk = 0; kk < 2; ++kk) {
            // ---- kk-boundary sync: counted, never drains mid-loop ----
            if (t == nt - 1 && kk == 1) {
                asm volatile("s_waitcnt vmcnt(0)" ::: "memory");
            } else {
                asm volatile("s_waitcnt vmcnt(4)" ::: "memory");
            }
            __builtin_amdgcn_sched_barrier(0);
            __builtin_amdgcn_s_barrier();
            __builtin_amdgcn_sched_barrier(0);

            const char* ka = kb + kk * 16384;           // A region, this k-half
            const char* kbB = kb + kk * 16384;          // B region base added via offB
            bh8 afr[4], bfr[4];

            // ---- P_even: reads (B all nf + A mf0-3), stage, barrier, MFMA ----
#pragma unroll
            for (int nf = 0; nf < 4; ++nf)
                bfr[nf] = *(const bh8*)(kbB + offB + nf * 1024);
#pragma unroll
            for (int i = 0; i < 4; ++i)
                afr[i] = *(const bh8*)(ka + offA + i * 1024);
            STAGE_G(t + 1, kk * 2);

            __builtin_amdgcn_sched_barrier(0);
            __builtin_amdgcn_s_barrier();
            __builtin_amdgcn_sched_barrier(0);

            __builtin_amdgcn_s_setprio(1);
#pragma unroll
            for (int i = 0; i < 4; ++i)
#pragma unroll
                for (int nf = 0; nf < 4; ++nf)
                    acc[i][nf] = __builtin_amdgcn_mfma_f32_16x16x32_bf16(
                        afr[i], bfr[nf], acc[i][nf], 0, 0, 0);
            __builtin_amdgcn_s_setprio(0);

            // ---- P_odd: reads (A mf4-7), stage, barrier, MFMA ----
#pragma unroll
            for (int i = 0; i < 4; ++i)
                afr[i] = *(const bh8*)(ka + offA + (4 + i) * 1024);
            STAGE_G(t + 1, kk * 2 + 1);

            __builtin_amdgcn_sched_barrier(0);
            __builtin_amdgcn_s_barrier();
            __builtin_amdgcn_sched_barrier(0);

            __builtin_amdgcn_s_setprio(1);
#pragma unroll
            for (int i = 0; i < 4; ++i)
#pragma unroll
                for (int nf = 0; nf < 4; ++nf)
                    acc[4 + i][nf] = __builtin_amdgcn_mfma_f32_16x16x32_bf16(
                        afr[i], bfr[nf], acc[4 + i][nf], 0, 0, 0);
            __builtin_amdgcn_s_setprio(0);
        }
    }

    // epilogue: C/D layout col=lane&15, row=(lane>>4)*4+reg
#pragma unroll
    for (int nf = 0; nf < 4; ++nf) {
        const int col = n0 + wn * 64 + nf * 16 + fr;
        const float bv = bias[col];
#pragma unroll
        for (int mf = 0; mf < 8; ++mf) {
            const int row = m0 + wm * 128 + mf * 16 + fg * 4;
#pragma unroll
            for (int r = 0; r < 4; ++r) {
                float v = (acc[mf][nf][r] + bv) * osc;
                if (OUTF)
                    ((float*)Cv)[(size_t)(row + r) * CC + col] = v;
                else
                    ((ushort*)Cv)[(size_t)(row + r) * CC + col] = f2bf(v);
            }
        }
    }
}

// ---------------------------------------------------------------------------
// Flash attention v11: 4 waves x 32 q-rows (was 8 x 16).
// Rationale (round-1 counters: MfmaUtil 27.8, VALUBusy 55, 0 bank conflicts):
// every wave reads the FULL K and V LDS tiles (shared MFMA operands), so
// wave-count is pure read redundancy. 32 q-rows/wave = 2 B-fragments per
// K-fragment read -> LDS read bytes and ds-addressing VALU per FLOP halved;
// MFMA work unchanged; 2 independent MFMA chains per wave (ILP) offset the
// occupancy drop (VGPR ~180, 2 waves/SIMD, 2 blocks/CU).
// Also: softmax denominator now accumulated via an all-ones B-fragment MFMA
// (o_l = mfma(pf, ones, o_l)): sums each P row over all 32 k-slots in the
// matrix pipe, replicated per-lane in D-layout -> removes 16 VALU adds per
// lane per tile-step AND all epilogue shuffles; l sums the same bf16-rounded
// P as the numerator.
// Unchanged: KVBLK=64, dbuf K/V via global_load_lds (now 8 loads/thread,
// vmcnt(8)), max-free exp2 softmax, diagonal-tile skip, tile pairing,
// XCD swizzle, K/V LDS XOR layouts.
// ---------------------------------------------------------------------------
__global__ __launch_bounds__(256, 2) void flash_attn_k(
    const ushort* __restrict__ Qm, const ushort* __restrict__ Km,
    const ushort* __restrict__ Vt, ushort* __restrict__ Om,
    const int* __restrict__ causal_p)
{
    __shared__ __align__(16) char Ksm[2][16384];   // [buf][kv=64][d=128] bf16
    __shared__ __align__(16) char Vsm[2][16384];   // [buf][d=128][pos=64] bf16

    const int tid = (int)threadIdx.x;
    const int lane = tid & 63, wave = tid >> 6;    // 4 waves
    const int fr = lane & 15, fg = lane >> 4;
    const int causal = causal_p[0];

    const int d_raw = (int)blockIdx.x + 8 * ((int)blockIdx.y + 16 * (int)blockIdx.z);
    const int xcd = d_raw & 7, jj = d_raw >> 3;
    const int head_lin = xcd * 8 + (jj & 7);
    const int pi = jj >> 3;                   // 0..7 (pair index)
    const int h = head_lin & 15, b = head_lin >> 4;

    const ushort* Qp = Qm + (size_t)b * TT * CC + h * DD;
    const ushort* Kp = Km + (size_t)b * TT * CC + h * DD;
    const ushort* Vp = Vt + (size_t)(b * HH + h) * DD * TT;
    ushort* Op = Om + (size_t)b * TT * CC + h * DD;

    // all-ones bf16 B-fragment for the row-sum MFMA
    const bh8 onesf = {0x3F80, 0x3F80, 0x3F80, 0x3F80,
                       0x3F80, 0x3F80, 0x3F80, 0x3F80};

    auto STAGE = [&](int ti, int buf) {
        const int kv0 = ti * 64;
#pragma unroll
        for (int c = 0; c < 4; ++c) {
            const int u = c * 256 + tid;
            const int r0 = u >> 4, s0 = u & 15;
            async16(Kp + (size_t)(kv0 + r0) * CC + (s0 ^ (r0 & 15)) * 8,
                    Ksm[buf] + (size_t)u * 16);
        }
#pragma unroll
        for (int c = 0; c < 4; ++c) {
            const int u = c * 256 + tid;
            const int d0 = u >> 3, s0 = u & 7;
            async16(Vp + (size_t)d0 * TT + kv0 + (s0 ^ (d0 & 7)) * 8,
                    Vsm[buf] + (size_t)u * 16);
        }
    };

#pragma unroll 1
    for (int pp = 0; pp < 2; ++pp) {
        const int tile = pp ? (15 - pi) : pi;
        const int q0 = tile * 128;
        const int qbase = q0 + wave * 32;         // 32 q-rows per wave

        bh8 qf[2][4];
#pragma unroll
        for (int qq = 0; qq < 2; ++qq)
#pragma unroll
            for (int s = 0; s < 4; ++s)
                qf[qq][s] = *(const bh8*)&Qp[(size_t)(qbase + qq * 16 + fr) * CC +
                                             s * 32 + fg * 8];

        fx4 o[2][8];
#pragma unroll
        for (int qq = 0; qq < 2; ++qq)
#pragma unroll
            for (int jn = 0; jn < 8; ++jn) o[qq][jn] = (fx4){0.f, 0.f, 0.f, 0.f};
        fx4 o_l[2];
        o_l[0] = (fx4){0.f, 0.f, 0.f, 0.f};
        o_l[1] = (fx4){0.f, 0.f, 0.f, 0.f};

        const int nfull  = causal ? (q0 >> 6) : (TT / 64);
        const int ntiles = causal ? (nfull + 2) : (TT / 64);

        STAGE(0, 0);
#pragma unroll 1
        for (int t = 0; t < ntiles; ++t) {
            const bool last = (t == ntiles - 1);
            if (!last) STAGE(t + 1, (t + 1) & 1);
            if (!last) { asm volatile("s_waitcnt vmcnt(8)" ::: "memory"); }
            else       { asm volatile("s_waitcnt vmcnt(0)" ::: "memory"); }
            __builtin_amdgcn_sched_barrier(0);
            __builtin_amdgcn_s_barrier();
            __builtin_amdgcn_sched_barrier(0);

            const int kv0 = t * 64;
            const char* kb = Ksm[t & 1];
            const char* vb = Vsm[t & 1];
            const bool domask = causal && (t >= nfull);
            const bool active = !domask || (kv0 <= qbase + 31);

            if (active) {
                // ---- QK^T, swapped: lane holds q=fr (per frag), kv=j*16+fg*4+r
                fx4 s4[2][4];
#pragma unroll
                for (int qq = 0; qq < 2; ++qq)
#pragma unroll
                    for (int j = 0; j < 4; ++j) s4[qq][j] = (fx4){0.f, 0.f, 0.f, 0.f};
                __builtin_amdgcn_s_setprio(1);
#pragma unroll
                for (int st = 0; st < 4; ++st) {
                    bh8 kf[4];
#pragma unroll
                    for (int j = 0; j < 4; ++j)
                        kf[j] = *(const bh8*)(kb + (j * 16 + fr) * 256 +
                                              ((st * 64 + fg * 16) ^ (fr << 4)));
#pragma unroll
                    for (int j = 0; j < 4; ++j) {
                        s4[0][j] = __builtin_amdgcn_mfma_f32_16x16x32_bf16(
                            kf[j], qf[0][st], s4[0][j], 0, 0, 0);
                        s4[1][j] = __builtin_amdgcn_mfma_f32_16x16x32_bf16(
                            kf[j], qf[1][st], s4[1][j], 0, 0, 0);
                    }
                }
                __builtin_amdgcn_s_setprio(0);

                // ---- softmax + PV per 32-kv half; P never leaves registers
#pragma unroll
                for (int g = 0; g < 2; ++g) {
                    bh8 pf[2];
#pragma unroll
                    for (int qq = 0; qq < 2; ++qq) {
                        const int q_idx = qbase + qq * 16 + fr;
                        float pg[2][4];
#pragma unroll
                        for (int j2 = 0; j2 < 2; ++j2) {
                            const int jb = g * 2 + j2;
#pragma unroll
                            for (int r = 0; r < 4; ++r) {
                                float v = s4[qq][jb][r];
                                if (domask && (kv0 + jb * 16 + fg * 4 + r > q_idx))
                                    v = -1e30f;
                                pg[j2][r] = exp2f(v);
                            }
                        }
                        union { uint u[4]; bh8 h; } pk;
                        asm("v_cvt_pk_bf16_f32 %0, %1, %2"
                            : "=v"(pk.u[0]) : "v"(pg[0][0]), "v"(pg[0][1]));
                        asm("v_cvt_pk_bf16_f32 %0, %1, %2"
                            : "=v"(pk.u[1]) : "v"(pg[0][2]), "v"(pg[0][3]));
                        asm("v_cvt_pk_bf16_f32 %0, %1, %2"
                            : "=v"(pk.u[2]) : "v"(pg[1][0]), "v"(pg[1][1]));
                        asm("v_cvt_pk_bf16_f32 %0, %1, %2"
                            : "=v"(pk.u[3]) : "v"(pg[1][2]), "v"(pg[1][3]));
                        pf[qq] = pk.h;
                        // denominator: row-sum over this 32-kv half in the
                        // matrix pipe; D-layout row = fg*4+r, replicated on fr
                        o_l[qq] = __builtin_amdgcn_mfma_f32_16x16x32_bf16(
                            pf[qq], onesf, o_l[qq], 0, 0, 0);
                    }

                    __builtin_amdgcn_s_setprio(1);
#pragma unroll
                    for (int jn = 0; jn < 8; ++jn) {
                        bh8 vf = *(const bh8*)(vb + (jn * 16 + fr) * 128 +
                                               ((g * 64 + fg * 16) ^ ((fr & 7) << 4)));
                        o[0][jn] = __builtin_amdgcn_mfma_f32_16x16x32_bf16(
                            pf[0], vf, o[0][jn], 0, 0, 0);
                        o[1][jn] = __builtin_amdgcn_mfma_f32_16x16x32_bf16(
                            pf[1], vf, o[1][jn], 0, 0, 0);
                    }
                    __builtin_amdgcn_s_setprio(0);
                }
            }

            __builtin_amdgcn_sched_barrier(0);
            __builtin_amdgcn_s_barrier();
            __builtin_amdgcn_sched_barrier(0);
        }

        // ---- epilogue: l already per-lane in D-layout (no shuffles)
#pragma unroll
        for (int qq = 0; qq < 2; ++qq)
#pragma unroll
            for (int r = 0; r < 4; ++r) {
                const float inv = 1.0f / o_l[qq][r];
                const size_t rowoff = (size_t)(qbase + qq * 16 + fg * 4 + r) * CC;
#pragma unroll
                for (int jn = 0; jn < 8; ++jn)
                    Op[rowoff + jn * 16 + fr] = f2bf(o[qq][jn][r] * inv);
            }
    }
}

// ---------------------------------------------------------------------------
extern "C" void kernel_launch(void* const* d_in, const int* in_sizes, int n_in,
                              void* d_out, int out_size, void* d_ws, size_t ws_size,
                              hipStream_t stream)
{
    (void)in_sizes; (void)n_in; (void)out_size;
    const float* querys = (const float*)d_in[0];
    const float* keys   = (const float*)d_in[1];
    const float* values = (const float*)d_in[2];
    const float* Wq = (const float*)d_in[3];
    const float* bq = (const float*)d_in[4];
    const float* Wk = (const float*)d_in[5];
    const float* bk = (const float*)d_in[6];
    const float* Wv = (const float*)d_in[7];
    const float* bv = (const float*)d_in[8];
    const float* Wo = (const float*)d_in[9];
    const float* bo = (const float*)d_in[10];
    const int* is_causal = (const int*)d_in[11];

    const size_t WBYTES = (size_t)CC * CC * 2;   // 8 MiB per weight
    const size_t XBYTES = (size_t)MM * CC * 2;   // 32 MiB per activation
    if (ws_size < 4 * WBYTES + 4 * XBYTES) return;  // need 160 MiB

    uint8_t* ws = (uint8_t*)d_ws;
    ushort* WqT = (ushort*)(ws);
    ushort* WkT = (ushort*)(ws + WBYTES);
    ushort* WvT = (ushort*)(ws + 2 * WBYTES);
    ushort* WoT = (ushort*)(ws + 3 * WBYTES);
    uint8_t* act = ws + 4 * WBYTES;
    ushort* Xq = (ushort*)(act);                 // later: Kb
    ushort* Xk = (ushort*)(act + XBYTES);        // later: Vb, then attn-out
    ushort* Xv = (ushort*)(act + 2 * XBYTES);    // later: Vt
    ushort* Qb = (ushort*)(act + 3 * XBYTES);
    ushort* Kb = Xq;
    ushort* Vb = Xk;
    ushort* Vt = Xv;
    ushort* Ob = Xk;   // attn output overwrites Vb (dead after transpose_v)

    dim3 tb(32, 8);
    transpose4_w_k<<<dim3(CC / 32, CC / 32, 4), tb, 0, stream>>>(
        Wq, Wk, Wv, Wo, WqT, WkT, WvT, WoT);

    const int nX = MM * CC;
    convert3_k<<<dim3(nX / 4 / 256, 3), 256, 0, stream>>>(
        querys, keys, values, Xq, Xk, Xv, nX);

    dim3 gg((MM / 256) * (CC / 256));   // 32 x 8 = 256 blocks, 1 per CU

    // softmax scale folded into Q projection (exp2 domain): log2(e)/sqrt(128)
    const float QSC = 0.12751789836306614f;

    gemm_bf16_k<0><<<gg, 512, 0, stream>>>(Xq, WqT, bq, Qb, QSC);
    gemm_bf16_k<0><<<gg, 512, 0, stream>>>(Xk, WkT, bk, Kb, 1.0f);
    gemm_bf16_k<0><<<gg, 512, 0, stream>>>(Xv, WvT, bv, Vb, 1.0f);

    dim3 gvt(DD / 32, TT / 32, BB * HH);
    transpose_v_k<<<gvt, tb, 0, stream>>>(Vb, Vt);

    dim3 ga(8, HH, BB);   // pair index x head x batch, 256 threads (4 waves)
    flash_attn_k<<<ga, 256, 0, stream>>>(Qb, Kb, Vt, Ob, is_causal);

    gemm_bf16_k<1><<<gg, 512, 0, stream>>>(Ob, WoT, bo, d_out, 1.0f);
}

// Round 3
// 456.785 us; speedup vs baseline: 1.1283x; 1.1283x over previous
//
#include <hip/hip_runtime.h>
#include <hip/hip_bf16.h>
#include <stdint.h>

// Problem constants
#define BB 4
#define TT 2048
#define CC 2048
#define HH 16
#define DD 128
#define MM (BB*TT)   // 8192 rows

typedef __attribute__((ext_vector_type(8))) short bh8;   // 8 bf16 (4 VGPRs)
typedef __attribute__((ext_vector_type(4))) float fx4;   // MFMA 16x16 accumulator

__device__ inline ushort f2bf(float x) {
    union { float f; uint32_t u; } c; c.f = x;
    uint32_t lsb = (c.u >> 16) & 1u;
    return (ushort)((c.u + 0x7fffu + lsb) >> 16);
}

__device__ inline void async16(const void* g, void* l) {
    __builtin_amdgcn_global_load_lds(
        (const __attribute__((address_space(1))) uint32_t*)g,
        (__attribute__((address_space(3))) uint32_t*)l, 16, 0, 0);
}

// ---------------------------------------------------------------------------
// Fused fp32 -> bf16 convert for all 3 inputs (blockIdx.y selects tensor)
// ---------------------------------------------------------------------------
__global__ __launch_bounds__(256) void convert3_k(
    const float* __restrict__ i0, const float* __restrict__ i1,
    const float* __restrict__ i2,
    ushort* __restrict__ o0, ushort* __restrict__ o1, ushort* __restrict__ o2,
    int n)
{
    const float* in; ushort* out;
    switch (blockIdx.y) {
        case 0:  in = i0; out = o0; break;
        case 1:  in = i1; out = o1; break;
        default: in = i2; out = o2; break;
    }
    int i = (int)(blockIdx.x * 256 + threadIdx.x) * 4;
    if (i + 3 < n) {
        float4 v = *(const float4*)&in[i];
        ushort4 o;
        o.x = f2bf(v.x); o.y = f2bf(v.y); o.z = f2bf(v.z); o.w = f2bf(v.w);
        *(ushort4*)&out[i] = o;
    }
}

// ---------------------------------------------------------------------------
// Fused weight transpose+convert for all 4 weights (blockIdx.z selects).
// W[k][n] fp32 -> Wt[n][k] bf16 (CC x CC), ushort2 stores.
// ---------------------------------------------------------------------------
__global__ __launch_bounds__(256) void transpose4_w_k(
    const float* __restrict__ w0, const float* __restrict__ w1,
    const float* __restrict__ w2, const float* __restrict__ w3,
    ushort* __restrict__ t0, ushort* __restrict__ t1,
    ushort* __restrict__ t2, ushort* __restrict__ t3)
{
    const float* W; ushort* Wt;
    switch (blockIdx.z) {
        case 0:  W = w0; Wt = t0; break;
        case 1:  W = w1; Wt = t1; break;
        case 2:  W = w2; Wt = t2; break;
        default: W = w3; Wt = t3; break;
    }
    __shared__ __align__(16) ushort tile[32][33];
    const int n0 = blockIdx.x * 32, k0 = blockIdx.y * 32;
    const int tx = threadIdx.x, ty = threadIdx.y;   // (32, 8)
#pragma unroll
    for (int r = 0; r < 32; r += 8)
        tile[ty + r][tx] = f2bf(W[(size_t)(k0 + ty + r) * CC + n0 + tx]);  // [kl][nl]
    __syncthreads();
    const int tid = ty * 32 + tx;
    const int p = tid & 15;        // k-pair index
    const int row = tid >> 4;      // 0..15
#pragma unroll
    for (int rr = 0; rr < 2; ++rr) {
        const int n_row = row + rr * 16;
        ushort2 w2;
        w2.x = tile[2 * p][n_row];
        w2.y = tile[2 * p + 1][n_row];
        *(ushort2*)&Wt[(size_t)(n0 + n_row) * CC + k0 + 2 * p] = w2;
    }
}

// ---------------------------------------------------------------------------
// V transpose per head: V[b,t,h*D+d] bf16 -> Vt[((b*H+h)*D+d)*T + pnew(t)]
// pnew: within each 32-aligned t-block, with t = jj*16 + fg*4 + r:
//   p = fg*8 + jj*4 + r  (PV A-fragment k-slot order of swapped-QK^T softmax)
// ---------------------------------------------------------------------------
__global__ __launch_bounds__(256) void transpose_v_k(
    const ushort* __restrict__ V, ushort* __restrict__ Vt)
{
    __shared__ __align__(16) ushort tile[32][33];
    const int bh = blockIdx.z;
    const int b = bh >> 4, h = bh & 15;
    const int t0 = blockIdx.y * 32, d0 = blockIdx.x * 32;
    const int tx = threadIdx.x, ty = threadIdx.y;   // (32, 8)
    const ushort* Vp = V + (size_t)b * TT * CC + h * DD;
#pragma unroll
    for (int r = 0; r < 32; r += 8)
        tile[ty + r][tx] = Vp[(size_t)(t0 + ty + r) * CC + d0 + tx];  // [t][d]
    __syncthreads();
    ushort* Vtp = Vt + (size_t)bh * DD * TT;
    const int tt = t0 + tx;
    const int pnew = (tt & ~31) | (((tt >> 2) & 3) << 3) | (((tt >> 4) & 1) << 2) | (tt & 3);
#pragma unroll
    for (int r = 0; r < 32; r += 8)
        Vtp[(size_t)(d0 + ty + r) * TT + pnew] = tile[tx][ty + r];
}

// ---------------------------------------------------------------------------
// GEMM v9: m201-template port, K-HALF granularity, 256x256 tile, BK=64,
// 8 waves (2M x 4N). NEW in v9: XCD-locality block remap.
// Old: n_tile = bid&7 -> with XCD = bid%8 each XCD pinned ONE B-panel (1MB,
// L2-resident) but streamed the ENTIRE 32MB A matrix (A fetched 8x = 256MB
// per GEMM, ~40us HBM per GEMM).
// New: xcd = bid&7 owns a contiguous 4-m_tile A range (4MB, fetched once)
// and its 32 blocks share B K-slices via L2 (B fetched 8x = 64MB total).
// Per-GEMM fetch ~290MB -> ~100MB. Inner loop unchanged.
// ---------------------------------------------------------------------------
template<int OUTF>
__global__ __launch_bounds__(512, 2) void gemm_bf16_k(
    const ushort* __restrict__ A, const ushort* __restrict__ Bt,
    const float* __restrict__ bias, void* __restrict__ Cv, float osc)
{
    __shared__ __align__(16) char Gsm[2][65536];  // [dbuf][A.k0|A.k1|B.k0|B.k1]

    const int tid = (int)threadIdx.x;
    const int lane = tid & 63, wave = tid >> 6;
    const int fr = lane & 15, fg = lane >> 4;      // frag row / k-slot group
    const int wm = wave >> 2, wn = wave & 3;       // 2m x 4n wave grid

    // XCD-locality remap: xcd = bid%8 (dispatch round-robin), 32 blocks/XCD
    // cover m_tiles [xcd*4, xcd*4+4) x n_tiles [0,8); n fastest so blocks
    // adjacent in launch order share an A panel.
    const int bid = (int)blockIdx.x;
    const int xcd = bid & 7, local = bid >> 3;
    const int m_tile = xcd * 4 + (local >> 3);
    const int n_tile = local & 7;
    const int m0 = m_tile * 256, n0 = n_tile * 256;

    const ushort* Ag = A  + (size_t)m0 * CC;
    const ushort* Bg = Bt + (size_t)n0 * CC;
    const int nt = CC / 64;                        // 32 K-tiles (BK=64)

    // stage group g of tile t: g0=A.k0 g1=B.k0 g2=A.k1 g3=B.k1 (2 loads)
    auto STAGE_G = [&](int t, int g) {
        if (t >= nt) return;
        const int khalf = g >> 1, isB = g & 1;
        char* base = Gsm[t & 1] + isB * 32768 + khalf * 16384;
        const ushort* src = isB ? Bg : Ag;
        const int kbase = t * 64 + khalf * 32;
#pragma unroll
        for (int l = 0; l < 2; ++l) {
            const int u = l * 512 + tid;
            const int j = u >> 3, s = u & 7;
            const int ek = s ^ (j & 7);
            const int e = (ek >> 2) & 1, ks = ek & 3;
            async16(src + (size_t)(2 * j + e) * CC + kbase + ks * 8,
                    base + u * 16);
        }
    };

    // fragment byte offsets within a 16KB region (pair-XOR; +16 rows = +1024)
    const int slot = ((((fr & 1) << 2) | fg) ^ ((fr >> 1) & 7));
    const int offA = (wm * 64 + (fr >> 1)) * 128 + slot * 16;           // +mf*1024
    const int offB = 32768 + (wn * 32 + (fr >> 1)) * 128 + slot * 16;   // +nf*1024

    fx4 acc[8][4];
#pragma unroll
    for (int i = 0; i < 8; ++i)
#pragma unroll
        for (int j = 0; j < 4; ++j)
            acc[i][j] = (fx4){0.f, 0.f, 0.f, 0.f};

    // prologue: tile 0 all 4 groups (8 loads/thread)
#pragma unroll
    for (int g = 0; g < 4; ++g) STAGE_G(0, g);

#pragma unroll 1
    for (int t = 0; t < nt; ++t) {
        const char* kb = Gsm[t & 1];
#pragma unroll
        for (int kk = 0; kk < 2; ++kk) {
            // ---- kk-boundary sync: counted, never drains mid-loop ----
            if (t == nt - 1 && kk == 1) {
                asm volatile("s_waitcnt vmcnt(0)" ::: "memory");
            } else {
                asm volatile("s_waitcnt vmcnt(4)" ::: "memory");
            }
            __builtin_amdgcn_sched_barrier(0);
            __builtin_amdgcn_s_barrier();
            __builtin_amdgcn_sched_barrier(0);

            const char* ka = kb + kk * 16384;           // A region, this k-half
            const char* kbB = kb + kk * 16384;          // B region base added via offB
            bh8 afr[4], bfr[4];

            // ---- P_even: reads (B all nf + A mf0-3), stage, barrier, MFMA ----
#pragma unroll
            for (int nf = 0; nf < 4; ++nf)
                bfr[nf] = *(const bh8*)(kbB + offB + nf * 1024);
#pragma unroll
            for (int i = 0; i < 4; ++i)
                afr[i] = *(const bh8*)(ka + offA + i * 1024);
            STAGE_G(t + 1, kk * 2);

            __builtin_amdgcn_sched_barrier(0);
            __builtin_amdgcn_s_barrier();
            __builtin_amdgcn_sched_barrier(0);

            __builtin_amdgcn_s_setprio(1);
#pragma unroll
            for (int i = 0; i < 4; ++i)
#pragma unroll
                for (int nf = 0; nf < 4; ++nf)
                    acc[i][nf] = __builtin_amdgcn_mfma_f32_16x16x32_bf16(
                        afr[i], bfr[nf], acc[i][nf], 0, 0, 0);
            __builtin_amdgcn_s_setprio(0);

            // ---- P_odd: reads (A mf4-7), stage, barrier, MFMA ----
#pragma unroll
            for (int i = 0; i < 4; ++i)
                afr[i] = *(const bh8*)(ka + offA + (4 + i) * 1024);
            STAGE_G(t + 1, kk * 2 + 1);

            __builtin_amdgcn_sched_barrier(0);
            __builtin_amdgcn_s_barrier();
            __builtin_amdgcn_sched_barrier(0);

            __builtin_amdgcn_s_setprio(1);
#pragma unroll
            for (int i = 0; i < 4; ++i)
#pragma unroll
                for (int nf = 0; nf < 4; ++nf)
                    acc[4 + i][nf] = __builtin_amdgcn_mfma_f32_16x16x32_bf16(
                        afr[i], bfr[nf], acc[4 + i][nf], 0, 0, 0);
            __builtin_amdgcn_s_setprio(0);
        }
    }

    // epilogue: C/D layout col=lane&15, row=(lane>>4)*4+reg
#pragma unroll
    for (int nf = 0; nf < 4; ++nf) {
        const int col = n0 + wn * 64 + nf * 16 + fr;
        const float bv = bias[col];
#pragma unroll
        for (int mf = 0; mf < 8; ++mf) {
            const int row = m0 + wm * 128 + mf * 16 + fg * 4;
#pragma unroll
            for (int r = 0; r < 4; ++r) {
                float v = (acc[mf][nf][r] + bv) * osc;
                if (OUTF)
                    ((float*)Cv)[(size_t)(row + r) * CC + col] = v;
                else
                    ((ushort*)Cv)[(size_t)(row + r) * CC + col] = f2bf(v);
            }
        }
    }
}

// ---------------------------------------------------------------------------
// Flash attention v12: v10 structure (proven 108.8us: 8 waves x 16 q-rows,
// 512 threads, 16 waves/CU) + v11's ones-MFMA denominator.
// Round-2 lesson: attn is overlap/latency-bound, not LDS-BW-bound -> keep
// high wave count; VALU savings that cost occupancy regress.
// ones-MFMA: o_l = mfma(pf, ones, o_l) sums each P row over the 32-kv half
// in the matrix pipe; D layout row = fg*4+r matches the epilogue row
// directly -> removes 16 VALU adds/lane/tile AND all epilogue shuffles.
// ---------------------------------------------------------------------------
__global__ __launch_bounds__(512, 4) void flash_attn_k(
    const ushort* __restrict__ Qm, const ushort* __restrict__ Km,
    const ushort* __restrict__ Vt, ushort* __restrict__ Om,
    const int* __restrict__ causal_p)
{
    __shared__ __align__(16) char Ksm[2][16384];   // [buf][kv=64][d=128] bf16
    __shared__ __align__(16) char Vsm[2][16384];   // [buf][d=128][pos=64] bf16

    const int tid = (int)threadIdx.x;
    const int lane = tid & 63, wave = tid >> 6;
    const int fr = lane & 15, fg = lane >> 4;
    const int causal = causal_p[0];

    const int d_raw = (int)blockIdx.x + 8 * ((int)blockIdx.y + 16 * (int)blockIdx.z);
    const int xcd = d_raw & 7, jj = d_raw >> 3;
    const int head_lin = xcd * 8 + (jj & 7);
    const int pi = jj >> 3;                   // 0..7 (pair index)
    const int h = head_lin & 15, b = head_lin >> 4;

    const ushort* Qp = Qm + (size_t)b * TT * CC + h * DD;
    const ushort* Kp = Km + (size_t)b * TT * CC + h * DD;
    const ushort* Vp = Vt + (size_t)(b * HH + h) * DD * TT;
    ushort* Op = Om + (size_t)b * TT * CC + h * DD;

    // all-ones bf16 B-fragment for the row-sum MFMA
    const bh8 onesf = {0x3F80, 0x3F80, 0x3F80, 0x3F80,
                       0x3F80, 0x3F80, 0x3F80, 0x3F80};

    auto STAGE = [&](int ti, int buf) {
        const int kv0 = ti * 64;
        {
            const int r0 = tid >> 4, s0 = tid & 15;
            async16(Kp + (size_t)(kv0 + r0) * CC + (s0 ^ (r0 & 15)) * 8,
                    Ksm[buf] + tid * 16);
            async16(Kp + (size_t)(kv0 + 32 + r0) * CC + (s0 ^ (r0 & 15)) * 8,
                    Ksm[buf] + 8192 + tid * 16);
        }
        {
            const int d0 = tid >> 3, s0 = tid & 7;
            async16(Vp + (size_t)d0 * TT + kv0 + (s0 ^ (d0 & 7)) * 8,
                    Vsm[buf] + tid * 16);
            async16(Vp + (size_t)(64 + d0) * TT + kv0 + (s0 ^ (d0 & 7)) * 8,
                    Vsm[buf] + 8192 + tid * 16);
        }
    };

#pragma unroll 1
    for (int pp = 0; pp < 2; ++pp) {
        const int tile = pp ? (15 - pi) : pi;
        const int q0 = tile * 128;
        const int qbase = q0 + wave * 16;
        const int q_idx = qbase + fr;         // this lane's q-row (swapped layout)

        bh8 qf[4];
#pragma unroll
        for (int s = 0; s < 4; ++s)
            qf[s] = *(const bh8*)&Qp[(size_t)(qbase + fr) * CC + s * 32 + fg * 8];

        fx4 o[8];
#pragma unroll
        for (int jn = 0; jn < 8; ++jn) o[jn] = (fx4){0.f, 0.f, 0.f, 0.f};
        fx4 o_l = (fx4){0.f, 0.f, 0.f, 0.f};

        const int nfull  = causal ? (q0 >> 6) : (TT / 64);
        const int ntiles = causal ? (nfull + 2) : (TT / 64);

        STAGE(0, 0);
#pragma unroll 1
        for (int t = 0; t < ntiles; ++t) {
            const bool last = (t == ntiles - 1);
            if (!last) STAGE(t + 1, (t + 1) & 1);
            if (!last) { asm volatile("s_waitcnt vmcnt(4)" ::: "memory"); }
            else       { asm volatile("s_waitcnt vmcnt(0)" ::: "memory"); }
            __builtin_amdgcn_sched_barrier(0);
            __builtin_amdgcn_s_barrier();
            __builtin_amdgcn_sched_barrier(0);

            const int kv0 = t * 64;
            const char* kb = Ksm[t & 1];
            const char* vb = Vsm[t & 1];
            const bool domask = causal && (t >= nfull);
            const bool active = !domask || (kv0 <= qbase + 15);

            if (active) {
                // ---- QK^T, swapped: S^T layout; lane holds q=fr, kv=j*16+fg*4+r
                fx4 s4[4];
#pragma unroll
                for (int j = 0; j < 4; ++j) s4[j] = (fx4){0.f, 0.f, 0.f, 0.f};
                __builtin_amdgcn_s_setprio(1);
#pragma unroll
                for (int st = 0; st < 4; ++st) {
                    bh8 kf[4];
#pragma unroll
                    for (int j = 0; j < 4; ++j)
                        kf[j] = *(const bh8*)(kb + (j * 16 + fr) * 256 +
                                              ((st * 64 + fg * 16) ^ (fr << 4)));
#pragma unroll
                    for (int j = 0; j < 4; ++j)
                        s4[j] = __builtin_amdgcn_mfma_f32_16x16x32_bf16(
                            kf[j], qf[st], s4[j], 0, 0, 0);
                }
                __builtin_amdgcn_s_setprio(0);

                // ---- softmax + PV per 32-kv half; P never leaves registers
#pragma unroll
                for (int g = 0; g < 2; ++g) {
                    float pg[2][4];
#pragma unroll
                    for (int j2 = 0; j2 < 2; ++j2) {
                        const int jb = g * 2 + j2;
#pragma unroll
                        for (int r = 0; r < 4; ++r) {
                            float v = s4[jb][r];
                            if (domask && (kv0 + jb * 16 + fg * 4 + r > q_idx))
                                v = -1e30f;
                            pg[j2][r] = exp2f(v);
                        }
                    }
                    // pack to PV A-fragment: k-slot e = jj*4 + r
                    union { uint u[4]; bh8 h; } pk;
                    asm("v_cvt_pk_bf16_f32 %0, %1, %2"
                        : "=v"(pk.u[0]) : "v"(pg[0][0]), "v"(pg[0][1]));
                    asm("v_cvt_pk_bf16_f32 %0, %1, %2"
                        : "=v"(pk.u[1]) : "v"(pg[0][2]), "v"(pg[0][3]));
                    asm("v_cvt_pk_bf16_f32 %0, %1, %2"
                        : "=v"(pk.u[2]) : "v"(pg[1][0]), "v"(pg[1][1]));
                    asm("v_cvt_pk_bf16_f32 %0, %1, %2"
                        : "=v"(pk.u[3]) : "v"(pg[1][2]), "v"(pg[1][3]));
                    const bh8 pf = pk.h;

                    // denominator via matrix pipe: row-sum of this 32-kv half,
                    // D row = fg*4+r (matches epilogue rows), replicated on fr
                    o_l = __builtin_amdgcn_mfma_f32_16x16x32_bf16(
                        pf, onesf, o_l, 0, 0, 0);

                    __builtin_amdgcn_s_setprio(1);
#pragma unroll
                    for (int jn = 0; jn < 8; ++jn) {
                        bh8 vf = *(const bh8*)(vb + (jn * 16 + fr) * 128 +
                                               ((g * 64 + fg * 16) ^ ((fr & 7) << 4)));
                        o[jn] = __builtin_amdgcn_mfma_f32_16x16x32_bf16(
                            pf, vf, o[jn], 0, 0, 0);
                    }
                    __builtin_amdgcn_s_setprio(0);
                }
            }

            __builtin_amdgcn_sched_barrier(0);
            __builtin_amdgcn_s_barrier();
            __builtin_amdgcn_sched_barrier(0);
        }

        // ---- epilogue: l already per-lane in D-layout (no shuffles)
#pragma unroll
        for (int r = 0; r < 4; ++r) {
            const float inv = 1.0f / o_l[r];
            const size_t rowoff = (size_t)(qbase + fg * 4 + r) * CC;
#pragma unroll
            for (int jn = 0; jn < 8; ++jn)
                Op[rowoff + jn * 16 + fr] = f2bf(o[jn][r] * inv);
        }
    }
}

// ---------------------------------------------------------------------------
extern "C" void kernel_launch(void* const* d_in, const int* in_sizes, int n_in,
                              void* d_out, int out_size, void* d_ws, size_t ws_size,
                              hipStream_t stream)
{
    (void)in_sizes; (void)n_in; (void)out_size;
    const float* querys = (const float*)d_in[0];
    const float* keys   = (const float*)d_in[1];
    const float* values = (const float*)d_in[2];
    const float* Wq = (const float*)d_in[3];
    const float* bq = (const float*)d_in[4];
    const float* Wk = (const float*)d_in[5];
    const float* bk = (const float*)d_in[6];
    const float* Wv = (const float*)d_in[7];
    const float* bv = (const float*)d_in[8];
    const float* Wo = (const float*)d_in[9];
    const float* bo = (const float*)d_in[10];
    const int* is_causal = (const int*)d_in[11];

    const size_t WBYTES = (size_t)CC * CC * 2;   // 8 MiB per weight
    const size_t XBYTES = (size_t)MM * CC * 2;   // 32 MiB per activation
    if (ws_size < 4 * WBYTES + 4 * XBYTES) return;  // need 160 MiB

    uint8_t* ws = (uint8_t*)d_ws;
    ushort* WqT = (ushort*)(ws);
    ushort* WkT = (ushort*)(ws + WBYTES);
    ushort* WvT = (ushort*)(ws + 2 * WBYTES);
    ushort* WoT = (ushort*)(ws + 3 * WBYTES);
    uint8_t* act = ws + 4 * WBYTES;
    ushort* Xq = (ushort*)(act);                 // later: Kb
    ushort* Xk = (ushort*)(act + XBYTES);        // later: Vb, then attn-out
    ushort* Xv = (ushort*)(act + 2 * XBYTES);    // later: Vt
    ushort* Qb = (ushort*)(act + 3 * XBYTES);
    ushort* Kb = Xq;
    ushort* Vb = Xk;
    ushort* Vt = Xv;
    ushort* Ob = Xk;   // attn output overwrites Vb (dead after transpose_v)

    dim3 tb(32, 8);
    transpose4_w_k<<<dim3(CC / 32, CC / 32, 4), tb, 0, stream>>>(
        Wq, Wk, Wv, Wo, WqT, WkT, WvT, WoT);

    const int nX = MM * CC;
    convert3_k<<<dim3(nX / 4 / 256, 3), 256, 0, stream>>>(
        querys, keys, values, Xq, Xk, Xv, nX);

    dim3 gg((MM / 256) * (CC / 256));   // 32 x 8 = 256 blocks, 1 per CU

    // softmax scale folded into Q projection (exp2 domain): log2(e)/sqrt(128)
    const float QSC = 0.12751789836306614f;

    gemm_bf16_k<0><<<gg, 512, 0, stream>>>(Xq, WqT, bq, Qb, QSC);
    gemm_bf16_k<0><<<gg, 512, 0, stream>>>(Xk, WkT, bk, Kb, 1.0f);
    gemm_bf16_k<0><<<gg, 512, 0, stream>>>(Xv, WvT, bv, Vb, 1.0f);

    dim3 gvt(DD / 32, TT / 32, BB * HH);
    transpose_v_k<<<gvt, tb, 0, stream>>>(Vb, Vt);

    dim3 ga(8, HH, BB);   // pair index x head x batch, 512 threads
    flash_attn_k<<<ga, 512, 0, stream>>>(Qb, Kb, Vt, Ob, is_causal);

    gemm_bf16_k<1><<<gg, 512, 0, stream>>>(Ob, WoT, bo, d_out, 1.0f);
}

// Round 4
// 447.208 us; speedup vs baseline: 1.1524x; 1.0214x over previous
//
#include <hip/hip_runtime.h>
#include <hip/hip_bf16.h>
#include <stdint.h>

// Problem constants
#define BB 4
#define TT 2048
#define CC 2048
#define HH 16
#define DD 128
#define MM (BB*TT)   // 8192 rows

typedef __attribute__((ext_vector_type(8))) short bh8;   // 8 bf16 (4 VGPRs)
typedef __attribute__((ext_vector_type(4))) float fx4;   // MFMA 16x16 accumulator

__device__ inline ushort f2bf(float x) {
    union { float f; uint32_t u; } c; c.f = x;
    uint32_t lsb = (c.u >> 16) & 1u;
    return (ushort)((c.u + 0x7fffu + lsb) >> 16);
}

__device__ inline void async16(const void* g, void* l) {
    __builtin_amdgcn_global_load_lds(
        (const __attribute__((address_space(1))) uint32_t*)g,
        (__attribute__((address_space(3))) uint32_t*)l, 16, 0, 0);
}

// ---------------------------------------------------------------------------
// Fused fp32 -> bf16 convert for all 3 inputs (blockIdx.y selects tensor)
// ---------------------------------------------------------------------------
__global__ __launch_bounds__(256) void convert3_k(
    const float* __restrict__ i0, const float* __restrict__ i1,
    const float* __restrict__ i2,
    ushort* __restrict__ o0, ushort* __restrict__ o1, ushort* __restrict__ o2,
    int n)
{
    const float* in; ushort* out;
    switch (blockIdx.y) {
        case 0:  in = i0; out = o0; break;
        case 1:  in = i1; out = o1; break;
        default: in = i2; out = o2; break;
    }
    int i = (int)(blockIdx.x * 256 + threadIdx.x) * 4;
    if (i + 3 < n) {
        float4 v = *(const float4*)&in[i];
        ushort4 o;
        o.x = f2bf(v.x); o.y = f2bf(v.y); o.z = f2bf(v.z); o.w = f2bf(v.w);
        *(ushort4*)&out[i] = o;
    }
}

// ---------------------------------------------------------------------------
// Fused weight transpose+convert for all 4 weights (blockIdx.z selects).
// W[k][n] fp32 -> Wt[n][k] bf16 (CC x CC), ushort2 stores.
// ---------------------------------------------------------------------------
__global__ __launch_bounds__(256) void transpose4_w_k(
    const float* __restrict__ w0, const float* __restrict__ w1,
    const float* __restrict__ w2, const float* __restrict__ w3,
    ushort* __restrict__ t0, ushort* __restrict__ t1,
    ushort* __restrict__ t2, ushort* __restrict__ t3)
{
    const float* W; ushort* Wt;
    switch (blockIdx.z) {
        case 0:  W = w0; Wt = t0; break;
        case 1:  W = w1; Wt = t1; break;
        case 2:  W = w2; Wt = t2; break;
        default: W = w3; Wt = t3; break;
    }
    __shared__ __align__(16) ushort tile[32][33];
    const int n0 = blockIdx.x * 32, k0 = blockIdx.y * 32;
    const int tx = threadIdx.x, ty = threadIdx.y;   // (32, 8)
#pragma unroll
    for (int r = 0; r < 32; r += 8)
        tile[ty + r][tx] = f2bf(W[(size_t)(k0 + ty + r) * CC + n0 + tx]);  // [kl][nl]
    __syncthreads();
    const int tid = ty * 32 + tx;
    const int p = tid & 15;        // k-pair index
    const int row = tid >> 4;      // 0..15
#pragma unroll
    for (int rr = 0; rr < 2; ++rr) {
        const int n_row = row + rr * 16;
        ushort2 w2;
        w2.x = tile[2 * p][n_row];
        w2.y = tile[2 * p + 1][n_row];
        *(ushort2*)&Wt[(size_t)(n0 + n_row) * CC + k0 + 2 * p] = w2;
    }
}

// ---------------------------------------------------------------------------
// V transpose per head: V[b,t,h*D+d] bf16 -> Vt[((b*H+h)*D+d)*T + pnew(t)]
// pnew: within each 32-aligned t-block, with t = jj*16 + fg*4 + r:
//   p = fg*8 + jj*4 + r  (PV A-fragment k-slot order of swapped-QK^T softmax)
// ---------------------------------------------------------------------------
__global__ __launch_bounds__(256) void transpose_v_k(
    const ushort* __restrict__ V, ushort* __restrict__ Vt)
{
    __shared__ __align__(16) ushort tile[32][33];
    const int bh = blockIdx.z;
    const int b = bh >> 4, h = bh & 15;
    const int t0 = blockIdx.y * 32, d0 = blockIdx.x * 32;
    const int tx = threadIdx.x, ty = threadIdx.y;   // (32, 8)
    const ushort* Vp = V + (size_t)b * TT * CC + h * DD;
#pragma unroll
    for (int r = 0; r < 32; r += 8)
        tile[ty + r][tx] = Vp[(size_t)(t0 + ty + r) * CC + d0 + tx];  // [t][d]
    __syncthreads();
    ushort* Vtp = Vt + (size_t)bh * DD * TT;
    const int tt = t0 + tx;
    const int pnew = (tt & ~31) | (((tt >> 2) & 3) << 3) | (((tt >> 4) & 1) << 2) | (tt & 3);
#pragma unroll
    for (int r = 0; r < 32; r += 8)
        Vtp[(size_t)(d0 + ty + r) * TT + pnew] = tile[tx][ty + r];
}

// ---------------------------------------------------------------------------
// GEMM body (m201-template port, K-HALF granularity, 256x256 tile, BK=64,
// 8 waves 2M x 4N, XCD-locality remap from round 3). Shared by the fused
// QKV kernel and the output-projection kernel.
// ---------------------------------------------------------------------------
template<int OUTF>
__device__ __forceinline__ void gemm_body(
    const ushort* A, const ushort* Bt, const float* bias, void* Cv, float osc)
{
    __shared__ __align__(16) char Gsm[2][65536];  // [dbuf][A.k0|A.k1|B.k0|B.k1]

    const int tid = (int)threadIdx.x;
    const int lane = tid & 63, wave = tid >> 6;
    const int fr = lane & 15, fg = lane >> 4;      // frag row / k-slot group
    const int wm = wave >> 2, wn = wave & 3;       // 2m x 4n wave grid

    // XCD-locality remap: xcd = bid%8 (dispatch round-robin), 32 blocks/XCD
    // cover m_tiles [xcd*4, xcd*4+4) x n_tiles [0,8).
    const int bid = (int)blockIdx.x;
    const int xcd = bid & 7, local = bid >> 3;
    const int m_tile = xcd * 4 + (local >> 3);
    const int n_tile = local & 7;
    const int m0 = m_tile * 256, n0 = n_tile * 256;

    const ushort* Ag = A  + (size_t)m0 * CC;
    const ushort* Bg = Bt + (size_t)n0 * CC;
    const int nt = CC / 64;                        // 32 K-tiles (BK=64)

    // stage group g of tile t: g0=A.k0 g1=B.k0 g2=A.k1 g3=B.k1 (2 loads)
    auto STAGE_G = [&](int t, int g) {
        if (t >= nt) return;
        const int khalf = g >> 1, isB = g & 1;
        char* base = Gsm[t & 1] + isB * 32768 + khalf * 16384;
        const ushort* src = isB ? Bg : Ag;
        const int kbase = t * 64 + khalf * 32;
#pragma unroll
        for (int l = 0; l < 2; ++l) {
            const int u = l * 512 + tid;
            const int j = u >> 3, s = u & 7;
            const int ek = s ^ (j & 7);
            const int e = (ek >> 2) & 1, ks = ek & 3;
            async16(src + (size_t)(2 * j + e) * CC + kbase + ks * 8,
                    base + u * 16);
        }
    };

    // fragment byte offsets within a 16KB region (pair-XOR; +16 rows = +1024)
    const int slot = ((((fr & 1) << 2) | fg) ^ ((fr >> 1) & 7));
    const int offA = (wm * 64 + (fr >> 1)) * 128 + slot * 16;           // +mf*1024
    const int offB = 32768 + (wn * 32 + (fr >> 1)) * 128 + slot * 16;   // +nf*1024

    fx4 acc[8][4];
#pragma unroll
    for (int i = 0; i < 8; ++i)
#pragma unroll
        for (int j = 0; j < 4; ++j)
            acc[i][j] = (fx4){0.f, 0.f, 0.f, 0.f};

    // prologue: tile 0 all 4 groups (8 loads/thread)
#pragma unroll
    for (int g = 0; g < 4; ++g) STAGE_G(0, g);

#pragma unroll 1
    for (int t = 0; t < nt; ++t) {
        const char* kb = Gsm[t & 1];
#pragma unroll
        for (int kk = 0; kk < 2; ++kk) {
            // ---- kk-boundary sync: counted, never drains mid-loop ----
            if (t == nt - 1 && kk == 1) {
                asm volatile("s_waitcnt vmcnt(0)" ::: "memory");
            } else {
                asm volatile("s_waitcnt vmcnt(4)" ::: "memory");
            }
            __builtin_amdgcn_sched_barrier(0);
            __builtin_amdgcn_s_barrier();
            __builtin_amdgcn_sched_barrier(0);

            const char* ka = kb + kk * 16384;           // A region, this k-half
            const char* kbB = kb + kk * 16384;          // B region base added via offB
            bh8 afr[4], bfr[4];

            // ---- P_even: reads (B all nf + A mf0-3), stage, barrier, MFMA ----
#pragma unroll
            for (int nf = 0; nf < 4; ++nf)
                bfr[nf] = *(const bh8*)(kbB + offB + nf * 1024);
#pragma unroll
            for (int i = 0; i < 4; ++i)
                afr[i] = *(const bh8*)(ka + offA + i * 1024);
            STAGE_G(t + 1, kk * 2);

            __builtin_amdgcn_sched_barrier(0);
            __builtin_amdgcn_s_barrier();
            __builtin_amdgcn_sched_barrier(0);

            __builtin_amdgcn_s_setprio(1);
#pragma unroll
            for (int i = 0; i < 4; ++i)
#pragma unroll
                for (int nf = 0; nf < 4; ++nf)
                    acc[i][nf] = __builtin_amdgcn_mfma_f32_16x16x32_bf16(
                        afr[i], bfr[nf], acc[i][nf], 0, 0, 0);
            __builtin_amdgcn_s_setprio(0);

            // ---- P_odd: reads (A mf4-7), stage, barrier, MFMA ----
#pragma unroll
            for (int i = 0; i < 4; ++i)
                afr[i] = *(const bh8*)(ka + offA + (4 + i) * 1024);
            STAGE_G(t + 1, kk * 2 + 1);

            __builtin_amdgcn_sched_barrier(0);
            __builtin_amdgcn_s_barrier();
            __builtin_amdgcn_sched_barrier(0);

            __builtin_amdgcn_s_setprio(1);
#pragma unroll
            for (int i = 0; i < 4; ++i)
#pragma unroll
                for (int nf = 0; nf < 4; ++nf)
                    acc[4 + i][nf] = __builtin_amdgcn_mfma_f32_16x16x32_bf16(
                        afr[i], bfr[nf], acc[4 + i][nf], 0, 0, 0);
            __builtin_amdgcn_s_setprio(0);
        }
    }

    // epilogue: C/D layout col=lane&15, row=(lane>>4)*4+reg
#pragma unroll
    for (int nf = 0; nf < 4; ++nf) {
        const int col = n0 + wn * 64 + nf * 16 + fr;
        const float bv = bias[col];
#pragma unroll
        for (int mf = 0; mf < 8; ++mf) {
            const int row = m0 + wm * 128 + mf * 16 + fg * 4;
#pragma unroll
            for (int r = 0; r < 4; ++r) {
                float v = (acc[mf][nf][r] + bv) * osc;
                if (OUTF)
                    ((float*)Cv)[(size_t)(row + r) * CC + col] = v;
                else
                    ((ushort*)Cv)[(size_t)(row + r) * CC + col] = f2bf(v);
            }
        }
    }
}

// Fused Q/K/V projection GEMM: grid (256, 3), blockIdx.y selects tensor.
// 768 blocks backfill each other's tails (each GEMM alone is exactly
// 1 block/CU, so tails were idle CUs); saves 2 launch gaps. Flattened
// dispatch index % 8 == blockIdx.x % 8 -> XCD remap unchanged.
__global__ __launch_bounds__(512, 2) void gemm_qkv_k(
    const ushort* __restrict__ Xq, const ushort* __restrict__ Xk,
    const ushort* __restrict__ Xv,
    const ushort* __restrict__ WqT, const ushort* __restrict__ WkT,
    const ushort* __restrict__ WvT,
    const float* __restrict__ bq, const float* __restrict__ bk,
    const float* __restrict__ bv,
    ushort* __restrict__ Qb, ushort* __restrict__ Kb, ushort* __restrict__ Vb)
{
    const ushort* A; const ushort* Bt; const float* bias; ushort* Cv; float osc;
    switch (blockIdx.y) {
        case 0:  A = Xq; Bt = WqT; bias = bq; Cv = Qb;
                 osc = 0.12751789836306614f; break;   // log2(e)/sqrt(128)
        case 1:  A = Xk; Bt = WkT; bias = bk; Cv = Kb; osc = 1.0f; break;
        default: A = Xv; Bt = WvT; bias = bv; Cv = Vb; osc = 1.0f; break;
    }
    gemm_body<0>(A, Bt, bias, Cv, osc);
}

// Output projection GEMM (fp32 out)
__global__ __launch_bounds__(512, 2) void gemm_o_k(
    const ushort* __restrict__ A, const ushort* __restrict__ Bt,
    const float* __restrict__ bias, float* __restrict__ Cv)
{
    gemm_body<1>(A, Bt, bias, Cv, 1.0f);
}

// ---------------------------------------------------------------------------
// Flash attention v13: v12 (105.6us, MfmaUtil 30.3) with ONE barrier per
// KV-tile (was 2). STAGE moved AFTER the top barrier: the bottom barrier
// only existed to stop STAGE(t+2) (pre-barrier) clobbering buf[t&1] while
// slow waves read it; post-barrier STAGE makes the top barrier sufficient
// (post-barrier DMA lands >=400cy after pre-barrier ds_reads complete --
// same ordering argument as the m201 GEMM template). vmcnt ledger: at top
// of t only STAGE(t)'s 4 loads are outstanding -> vmcnt(0) == precise wait;
// STAGE(t+1) is in flight during all of compute(t) (>> HBM latency).
// Halves the per-tile all-wave sync cost (34 tiles/block).
// ---------------------------------------------------------------------------
__global__ __launch_bounds__(512, 4) void flash_attn_k(
    const ushort* __restrict__ Qm, const ushort* __restrict__ Km,
    const ushort* __restrict__ Vt, ushort* __restrict__ Om,
    const int* __restrict__ causal_p)
{
    __shared__ __align__(16) char Ksm[2][16384];   // [buf][kv=64][d=128] bf16
    __shared__ __align__(16) char Vsm[2][16384];   // [buf][d=128][pos=64] bf16

    const int tid = (int)threadIdx.x;
    const int lane = tid & 63, wave = tid >> 6;
    const int fr = lane & 15, fg = lane >> 4;
    const int causal = causal_p[0];

    const int d_raw = (int)blockIdx.x + 8 * ((int)blockIdx.y + 16 * (int)blockIdx.z);
    const int xcd = d_raw & 7, jj = d_raw >> 3;
    const int head_lin = xcd * 8 + (jj & 7);
    const int pi = jj >> 3;                   // 0..7 (pair index)
    const int h = head_lin & 15, b = head_lin >> 4;

    const ushort* Qp = Qm + (size_t)b * TT * CC + h * DD;
    const ushort* Kp = Km + (size_t)b * TT * CC + h * DD;
    const ushort* Vp = Vt + (size_t)(b * HH + h) * DD * TT;
    ushort* Op = Om + (size_t)b * TT * CC + h * DD;

    // all-ones bf16 B-fragment for the row-sum MFMA
    const bh8 onesf = {0x3F80, 0x3F80, 0x3F80, 0x3F80,
                       0x3F80, 0x3F80, 0x3F80, 0x3F80};

    auto STAGE = [&](int ti, int buf) {
        const int kv0 = ti * 64;
        {
            const int r0 = tid >> 4, s0 = tid & 15;
            async16(Kp + (size_t)(kv0 + r0) * CC + (s0 ^ (r0 & 15)) * 8,
                    Ksm[buf] + tid * 16);
            async16(Kp + (size_t)(kv0 + 32 + r0) * CC + (s0 ^ (r0 & 15)) * 8,
                    Ksm[buf] + 8192 + tid * 16);
        }
        {
            const int d0 = tid >> 3, s0 = tid & 7;
            async16(Vp + (size_t)d0 * TT + kv0 + (s0 ^ (d0 & 7)) * 8,
                    Vsm[buf] + tid * 16);
            async16(Vp + (size_t)(64 + d0) * TT + kv0 + (s0 ^ (d0 & 7)) * 8,
                    Vsm[buf] + 8192 + tid * 16);
        }
    };

#pragma unroll 1
    for (int pp = 0; pp < 2; ++pp) {
        const int tile = pp ? (15 - pi) : pi;
        const int q0 = tile * 128;
        const int qbase = q0 + wave * 16;
        const int q_idx = qbase + fr;         // this lane's q-row (swapped layout)

        bh8 qf[4];
#pragma unroll
        for (int s = 0; s < 4; ++s)
            qf[s] = *(const bh8*)&Qp[(size_t)(qbase + fr) * CC + s * 32 + fg * 8];

        fx4 o[8];
#pragma unroll
        for (int jn = 0; jn < 8; ++jn) o[jn] = (fx4){0.f, 0.f, 0.f, 0.f};
        fx4 o_l = (fx4){0.f, 0.f, 0.f, 0.f};

        const int nfull  = causal ? (q0 >> 6) : (TT / 64);
        const int ntiles = causal ? (nfull + 2) : (TT / 64);

        STAGE(0, 0);
#pragma unroll 1
        for (int t = 0; t < ntiles; ++t) {
            // top sync: own loads done -> barrier -> everyone's loads done
            asm volatile("s_waitcnt vmcnt(0)" ::: "memory");
            __builtin_amdgcn_sched_barrier(0);
            __builtin_amdgcn_s_barrier();
            __builtin_amdgcn_sched_barrier(0);
            if (t + 1 < ntiles) STAGE(t + 1, (t + 1) & 1);

            const int kv0 = t * 64;
            const char* kb = Ksm[t & 1];
            const char* vb = Vsm[t & 1];
            const bool domask = causal && (t >= nfull);
            const bool active = !domask || (kv0 <= qbase + 15);

            if (active) {
                // ---- QK^T, swapped: S^T layout; lane holds q=fr, kv=j*16+fg*4+r
                fx4 s4[4];
#pragma unroll
                for (int j = 0; j < 4; ++j) s4[j] = (fx4){0.f, 0.f, 0.f, 0.f};
                __builtin_amdgcn_s_setprio(1);
#pragma unroll
                for (int st = 0; st < 4; ++st) {
                    bh8 kf[4];
#pragma unroll
                    for (int j = 0; j < 4; ++j)
                        kf[j] = *(const bh8*)(kb + (j * 16 + fr) * 256 +
                                              ((st * 64 + fg * 16) ^ (fr << 4)));
#pragma unroll
                    for (int j = 0; j < 4; ++j)
                        s4[j] = __builtin_amdgcn_mfma_f32_16x16x32_bf16(
                            kf[j], qf[st], s4[j], 0, 0, 0);
                }
                __builtin_amdgcn_s_setprio(0);

                // ---- softmax + PV per 32-kv half; P never leaves registers
#pragma unroll
                for (int g = 0; g < 2; ++g) {
                    float pg[2][4];
#pragma unroll
                    for (int j2 = 0; j2 < 2; ++j2) {
                        const int jb = g * 2 + j2;
#pragma unroll
                        for (int r = 0; r < 4; ++r) {
                            float v = s4[jb][r];
                            if (domask && (kv0 + jb * 16 + fg * 4 + r > q_idx))
                                v = -1e30f;
                            pg[j2][r] = exp2f(v);
                        }
                    }
                    // pack to PV A-fragment: k-slot e = jj*4 + r
                    union { uint u[4]; bh8 h; } pk;
                    asm("v_cvt_pk_bf16_f32 %0, %1, %2"
                        : "=v"(pk.u[0]) : "v"(pg[0][0]), "v"(pg[0][1]));
                    asm("v_cvt_pk_bf16_f32 %0, %1, %2"
                        : "=v"(pk.u[1]) : "v"(pg[0][2]), "v"(pg[0][3]));
                    asm("v_cvt_pk_bf16_f32 %0, %1, %2"
                        : "=v"(pk.u[2]) : "v"(pg[1][0]), "v"(pg[1][1]));
                    asm("v_cvt_pk_bf16_f32 %0, %1, %2"
                        : "=v"(pk.u[3]) : "v"(pg[1][2]), "v"(pg[1][3]));
                    const bh8 pf = pk.h;

                    // denominator via matrix pipe: row-sum of this 32-kv half,
                    // D row = fg*4+r (matches epilogue rows), replicated on fr
                    o_l = __builtin_amdgcn_mfma_f32_16x16x32_bf16(
                        pf, onesf, o_l, 0, 0, 0);

                    __builtin_amdgcn_s_setprio(1);
#pragma unroll
                    for (int jn = 0; jn < 8; ++jn) {
                        bh8 vf = *(const bh8*)(vb + (jn * 16 + fr) * 128 +
                                               ((g * 64 + fg * 16) ^ ((fr & 7) << 4)));
                        o[jn] = __builtin_amdgcn_mfma_f32_16x16x32_bf16(
                            pf, vf, o[jn], 0, 0, 0);
                    }
                    __builtin_amdgcn_s_setprio(0);
                }
            }
        }

        // ---- epilogue: l already per-lane in D-layout (no shuffles)
#pragma unroll
        for (int r = 0; r < 4; ++r) {
            const float inv = 1.0f / o_l[r];
            const size_t rowoff = (size_t)(qbase + fg * 4 + r) * CC;
#pragma unroll
            for (int jn = 0; jn < 8; ++jn)
                Op[rowoff + jn * 16 + fr] = f2bf(o[jn][r] * inv);
        }
    }
}

// ---------------------------------------------------------------------------
extern "C" void kernel_launch(void* const* d_in, const int* in_sizes, int n_in,
                              void* d_out, int out_size, void* d_ws, size_t ws_size,
                              hipStream_t stream)
{
    (void)in_sizes; (void)n_in; (void)out_size;
    const float* querys = (const float*)d_in[0];
    const float* keys   = (const float*)d_in[1];
    const float* values = (const float*)d_in[2];
    const float* Wq = (const float*)d_in[3];
    const float* bq = (const float*)d_in[4];
    const float* Wk = (const float*)d_in[5];
    const float* bk = (const float*)d_in[6];
    const float* Wv = (const float*)d_in[7];
    const float* bv = (const float*)d_in[8];
    const float* Wo = (const float*)d_in[9];
    const float* bo = (const float*)d_in[10];
    const int* is_causal = (const int*)d_in[11];

    const size_t WBYTES = (size_t)CC * CC * 2;   // 8 MiB per weight
    const size_t XBYTES = (size_t)MM * CC * 2;   // 32 MiB per activation
    if (ws_size < 4 * WBYTES + 4 * XBYTES) return;  // need 160 MiB

    uint8_t* ws = (uint8_t*)d_ws;
    ushort* WqT = (ushort*)(ws);
    ushort* WkT = (ushort*)(ws + WBYTES);
    ushort* WvT = (ushort*)(ws + 2 * WBYTES);
    ushort* WoT = (ushort*)(ws + 3 * WBYTES);
    uint8_t* act = ws + 4 * WBYTES;
    ushort* Xq = (ushort*)(act);                 // later: Kb
    ushort* Xk = (ushort*)(act + XBYTES);        // later: Vb, then attn-out
    ushort* Xv = (ushort*)(act + 2 * XBYTES);    // later: Vt
    ushort* Qb = (ushort*)(act + 3 * XBYTES);
    ushort* Kb = Xq;
    ushort* Vb = Xk;
    ushort* Vt = Xv;
    ushort* Ob = Xk;   // attn output overwrites Vb (dead after transpose_v)

    dim3 tb(32, 8);
    transpose4_w_k<<<dim3(CC / 32, CC / 32, 4), tb, 0, stream>>>(
        Wq, Wk, Wv, Wo, WqT, WkT, WvT, WoT);

    const int nX = MM * CC;
    convert3_k<<<dim3(nX / 4 / 256, 3), 256, 0, stream>>>(
        querys, keys, values, Xq, Xk, Xv, nX);

    // fused Q/K/V projections: 768 blocks, tails backfill
    gemm_qkv_k<<<dim3((MM / 256) * (CC / 256), 3), 512, 0, stream>>>(
        Xq, Xk, Xv, WqT, WkT, WvT, bq, bk, bv, Qb, Kb, Vb);

    dim3 gvt(DD / 32, TT / 32, BB * HH);
    transpose_v_k<<<gvt, tb, 0, stream>>>(Vb, Vt);

    dim3 ga(8, HH, BB);   // pair index x head x batch, 512 threads
    flash_attn_k<<<ga, 512, 0, stream>>>(Qb, Kb, Vt, Ob, is_causal);

    gemm_o_k<<<dim3((MM / 256) * (CC / 256)), 512, 0, stream>>>(
        Ob, WoT, bo, (float*)d_out);
}

// Round 5
// 447.190 us; speedup vs baseline: 1.1525x; 1.0000x over previous
//
#include <hip/hip_runtime.h>
#include <hip/hip_bf16.h>
#include <stdint.h>

// Problem constants
#define BB 4
#define TT 2048
#define CC 2048
#define HH 16
#define DD 128
#define MM (BB*TT)   // 8192 rows

typedef __attribute__((ext_vector_type(8))) short bh8;   // 8 bf16 (4 VGPRs)
typedef __attribute__((ext_vector_type(4))) float fx4;   // MFMA 16x16 accumulator

__device__ inline ushort f2bf(float x) {
    union { float f; uint32_t u; } c; c.f = x;
    uint32_t lsb = (c.u >> 16) & 1u;
    return (ushort)((c.u + 0x7fffu + lsb) >> 16);
}

__device__ inline void async16(const void* g, void* l) {
    __builtin_amdgcn_global_load_lds(
        (const __attribute__((address_space(1))) uint32_t*)g,
        (__attribute__((address_space(3))) uint32_t*)l, 16, 0, 0);
}

// ---------------------------------------------------------------------------
// Fused fp32 -> bf16 convert for all 3 inputs (blockIdx.y selects tensor)
// ---------------------------------------------------------------------------
__global__ __launch_bounds__(256) void convert3_k(
    const float* __restrict__ i0, const float* __restrict__ i1,
    const float* __restrict__ i2,
    ushort* __restrict__ o0, ushort* __restrict__ o1, ushort* __restrict__ o2,
    int n)
{
    const float* in; ushort* out;
    switch (blockIdx.y) {
        case 0:  in = i0; out = o0; break;
        case 1:  in = i1; out = o1; break;
        default: in = i2; out = o2; break;
    }
    int i = (int)(blockIdx.x * 256 + threadIdx.x) * 4;
    if (i + 3 < n) {
        float4 v = *(const float4*)&in[i];
        ushort4 o;
        o.x = f2bf(v.x); o.y = f2bf(v.y); o.z = f2bf(v.z); o.w = f2bf(v.w);
        *(ushort4*)&out[i] = o;
    }
}

// ---------------------------------------------------------------------------
// Fused weight transpose+convert for all 4 weights (blockIdx.z selects).
// W[k][n] fp32 -> Wt[n][k] bf16 (CC x CC), ushort2 stores.
// ---------------------------------------------------------------------------
__global__ __launch_bounds__(256) void transpose4_w_k(
    const float* __restrict__ w0, const float* __restrict__ w1,
    const float* __restrict__ w2, const float* __restrict__ w3,
    ushort* __restrict__ t0, ushort* __restrict__ t1,
    ushort* __restrict__ t2, ushort* __restrict__ t3)
{
    const float* W; ushort* Wt;
    switch (blockIdx.z) {
        case 0:  W = w0; Wt = t0; break;
        case 1:  W = w1; Wt = t1; break;
        case 2:  W = w2; Wt = t2; break;
        default: W = w3; Wt = t3; break;
    }
    __shared__ __align__(16) ushort tile[32][33];
    const int n0 = blockIdx.x * 32, k0 = blockIdx.y * 32;
    const int tx = threadIdx.x, ty = threadIdx.y;   // (32, 8)
#pragma unroll
    for (int r = 0; r < 32; r += 8)
        tile[ty + r][tx] = f2bf(W[(size_t)(k0 + ty + r) * CC + n0 + tx]);  // [kl][nl]
    __syncthreads();
    const int tid = ty * 32 + tx;
    const int p = tid & 15;        // k-pair index
    const int row = tid >> 4;      // 0..15
#pragma unroll
    for (int rr = 0; rr < 2; ++rr) {
        const int n_row = row + rr * 16;
        ushort2 w2;
        w2.x = tile[2 * p][n_row];
        w2.y = tile[2 * p + 1][n_row];
        *(ushort2*)&Wt[(size_t)(n0 + n_row) * CC + k0 + 2 * p] = w2;
    }
}

// ---------------------------------------------------------------------------
// V transpose per head: V[b,t,h*D+d] bf16 -> Vt[((b*H+h)*D+d)*T + pnew(t)]
// pnew: within each 32-aligned t-block, with t = jj*16 + fg*4 + r:
//   p = fg*8 + jj*4 + r  (PV A-fragment k-slot order of swapped-QK^T softmax)
// ---------------------------------------------------------------------------
__global__ __launch_bounds__(256) void transpose_v_k(
    const ushort* __restrict__ V, ushort* __restrict__ Vt)
{
    __shared__ __align__(16) ushort tile[32][33];
    const int bh = blockIdx.z;
    const int b = bh >> 4, h = bh & 15;
    const int t0 = blockIdx.y * 32, d0 = blockIdx.x * 32;
    const int tx = threadIdx.x, ty = threadIdx.y;   // (32, 8)
    const ushort* Vp = V + (size_t)b * TT * CC + h * DD;
#pragma unroll
    for (int r = 0; r < 32; r += 8)
        tile[ty + r][tx] = Vp[(size_t)(t0 + ty + r) * CC + d0 + tx];  // [t][d]
    __syncthreads();
    ushort* Vtp = Vt + (size_t)bh * DD * TT;
    const int tt = t0 + tx;
    const int pnew = (tt & ~31) | (((tt >> 2) & 3) << 3) | (((tt >> 4) & 1) << 2) | (tt & 3);
#pragma unroll
    for (int r = 0; r < 32; r += 8)
        Vtp[(size_t)(d0 + ty + r) * TT + pnew] = tile[tx][ty + r];
}

// ---------------------------------------------------------------------------
// GEMM v10: single-vmcnt-per-K-tile ledger (m201-exact sync density).
// Round-4 counters (MfmaUtil 42, VALUBusy 20, HBM 10%) said the stall is
// exposed boundary sync, not ALU/BW. Changes vs v9:
//  - staging shifted one phase earlier: tile t phases stage
//    (t+1,g1),(t+1,g2),(t+1,g3),(t+2,g0); prologue stages t0.g0-g3 + t1.g0.
//  - kk0 boundary: vmcnt(2) (FIFO: 8 outstanding, completes ALL of tile t,
//    keeps t+1.g0's 2 loads in flight -> never drains). Last tile: vmcnt(0)
//    (vmcnt(2) would strand g3).
//  - kk1 boundary REMOVED (vmcnt + barrier): tile data fully guaranteed at
//    kk0 (per-wave vmcnt + barrier = all waves' DMAs done); the ph-mid
//    barriers bound wave skew to 1 interval, which orders the t+2.g0 write
//    into the current buffer >= 2 intervals after its last read (ph1).
// Per K-tile: 2 waits -> 1, 6 barriers -> 5, depth 8 -> 10 loads.
// ---------------------------------------------------------------------------
template<int OUTF>
__device__ __forceinline__ void gemm_body(
    const ushort* A, const ushort* Bt, const float* bias, void* Cv, float osc)
{
    __shared__ __align__(16) char Gsm[2][65536];  // [dbuf][A.k0|A.k1|B.k0|B.k1]

    const int tid = (int)threadIdx.x;
    const int lane = tid & 63, wave = tid >> 6;
    const int fr = lane & 15, fg = lane >> 4;      // frag row / k-slot group
    const int wm = wave >> 2, wn = wave & 3;       // 2m x 4n wave grid

    // XCD-locality remap: xcd = bid%8 (dispatch round-robin), 32 blocks/XCD
    // cover m_tiles [xcd*4, xcd*4+4) x n_tiles [0,8).
    const int bid = (int)blockIdx.x;
    const int xcd = bid & 7, local = bid >> 3;
    const int m_tile = xcd * 4 + (local >> 3);
    const int n_tile = local & 7;
    const int m0 = m_tile * 256, n0 = n_tile * 256;

    const ushort* Ag = A  + (size_t)m0 * CC;
    const ushort* Bg = Bt + (size_t)n0 * CC;
    const int nt = CC / 64;                        // 32 K-tiles (BK=64)

    // stage group g of tile t: g0=A.k0 g1=B.k0 g2=A.k1 g3=B.k1 (2 loads)
    auto STAGE_G = [&](int t, int g) {
        if (t >= nt) return;
        const int khalf = g >> 1, isB = g & 1;
        char* base = Gsm[t & 1] + isB * 32768 + khalf * 16384;
        const ushort* src = isB ? Bg : Ag;
        const int kbase = t * 64 + khalf * 32;
#pragma unroll
        for (int l = 0; l < 2; ++l) {
            const int u = l * 512 + tid;
            const int j = u >> 3, s = u & 7;
            const int ek = s ^ (j & 7);
            const int e = (ek >> 2) & 1, ks = ek & 3;
            async16(src + (size_t)(2 * j + e) * CC + kbase + ks * 8,
                    base + u * 16);
        }
    };

    // fragment byte offsets within a 16KB region (pair-XOR; +16 rows = +1024)
    const int slot = ((((fr & 1) << 2) | fg) ^ ((fr >> 1) & 7));
    const int offA = (wm * 64 + (fr >> 1)) * 128 + slot * 16;           // +mf*1024
    const int offB = 32768 + (wn * 32 + (fr >> 1)) * 128 + slot * 16;   // +nf*1024

    fx4 acc[8][4];
#pragma unroll
    for (int i = 0; i < 8; ++i)
#pragma unroll
        for (int j = 0; j < 4; ++j)
            acc[i][j] = (fx4){0.f, 0.f, 0.f, 0.f};

    // prologue: tile 0 all 4 groups + tile 1 group 0 (10 loads/thread)
#pragma unroll
    for (int g = 0; g < 4; ++g) STAGE_G(0, g);
    STAGE_G(1, 0);

#pragma unroll 1
    for (int t = 0; t < nt; ++t) {
        const char* kb = Gsm[t & 1];
#pragma unroll
        for (int kk = 0; kk < 2; ++kk) {
            // ---- tile boundary (kk0 only): counted, never drains mid-loop
            if (kk == 0) {
                if (t == nt - 1) {
                    asm volatile("s_waitcnt vmcnt(0)" ::: "memory");
                } else {
                    asm volatile("s_waitcnt vmcnt(2)" ::: "memory");
                }
                __builtin_amdgcn_sched_barrier(0);
                __builtin_amdgcn_s_barrier();
                __builtin_amdgcn_sched_barrier(0);
            }

            const char* ka = kb + kk * 16384;           // A region, this k-half
            const char* kbB = kb + kk * 16384;          // B region base added via offB
            bh8 afr[4], bfr[4];

            // ---- P_even: reads (B all nf + A mf0-3), stage, barrier, MFMA ----
#pragma unroll
            for (int nf = 0; nf < 4; ++nf)
                bfr[nf] = *(const bh8*)(kbB + offB + nf * 1024);
#pragma unroll
            for (int i = 0; i < 4; ++i)
                afr[i] = *(const bh8*)(ka + offA + i * 1024);
            STAGE_G(t + 1, kk ? 3 : 1);

            __builtin_amdgcn_sched_barrier(0);
            __builtin_amdgcn_s_barrier();
            __builtin_amdgcn_sched_barrier(0);

            __builtin_amdgcn_s_setprio(1);
#pragma unroll
            for (int i = 0; i < 4; ++i)
#pragma unroll
                for (int nf = 0; nf < 4; ++nf)
                    acc[i][nf] = __builtin_amdgcn_mfma_f32_16x16x32_bf16(
                        afr[i], bfr[nf], acc[i][nf], 0, 0, 0);
            __builtin_amdgcn_s_setprio(0);

            // ---- P_odd: reads (A mf4-7), stage, barrier, MFMA ----
#pragma unroll
            for (int i = 0; i < 4; ++i)
                afr[i] = *(const bh8*)(ka + offA + (4 + i) * 1024);
            if (kk) STAGE_G(t + 2, 0);
            else    STAGE_G(t + 1, 2);

            __builtin_amdgcn_sched_barrier(0);
            __builtin_amdgcn_s_barrier();
            __builtin_amdgcn_sched_barrier(0);

            __builtin_amdgcn_s_setprio(1);
#pragma unroll
            for (int i = 0; i < 4; ++i)
#pragma unroll
                for (int nf = 0; nf < 4; ++nf)
                    acc[4 + i][nf] = __builtin_amdgcn_mfma_f32_16x16x32_bf16(
                        afr[i], bfr[nf], acc[4 + i][nf], 0, 0, 0);
            __builtin_amdgcn_s_setprio(0);
        }
    }

    // epilogue: C/D layout col=lane&15, row=(lane>>4)*4+reg
#pragma unroll
    for (int nf = 0; nf < 4; ++nf) {
        const int col = n0 + wn * 64 + nf * 16 + fr;
        const float bv = bias[col];
#pragma unroll
        for (int mf = 0; mf < 8; ++mf) {
            const int row = m0 + wm * 128 + mf * 16 + fg * 4;
#pragma unroll
            for (int r = 0; r < 4; ++r) {
                float v = (acc[mf][nf][r] + bv) * osc;
                if (OUTF)
                    ((float*)Cv)[(size_t)(row + r) * CC + col] = v;
                else
                    ((ushort*)Cv)[(size_t)(row + r) * CC + col] = f2bf(v);
            }
        }
    }
}

// Fused Q/K/V projection GEMM: grid (256, 3), blockIdx.y selects tensor.
__global__ __launch_bounds__(512, 2) void gemm_qkv_k(
    const ushort* __restrict__ Xq, const ushort* __restrict__ Xk,
    const ushort* __restrict__ Xv,
    const ushort* __restrict__ WqT, const ushort* __restrict__ WkT,
    const ushort* __restrict__ WvT,
    const float* __restrict__ bq, const float* __restrict__ bk,
    const float* __restrict__ bv,
    ushort* __restrict__ Qb, ushort* __restrict__ Kb, ushort* __restrict__ Vb)
{
    const ushort* A; const ushort* Bt; const float* bias; ushort* Cv; float osc;
    switch (blockIdx.y) {
        case 0:  A = Xq; Bt = WqT; bias = bq; Cv = Qb;
                 osc = 0.12751789836306614f; break;   // log2(e)/sqrt(128)
        case 1:  A = Xk; Bt = WkT; bias = bk; Cv = Kb; osc = 1.0f; break;
        default: A = Xv; Bt = WvT; bias = bv; Cv = Vb; osc = 1.0f; break;
    }
    gemm_body<0>(A, Bt, bias, Cv, osc);
}

// Output projection GEMM (fp32 out)
__global__ __launch_bounds__(512, 2) void gemm_o_k(
    const ushort* __restrict__ A, const ushort* __restrict__ Bt,
    const float* __restrict__ bias, float* __restrict__ Cv)
{
    gemm_body<1>(A, Bt, bias, Cv, 1.0f);
}

// ---------------------------------------------------------------------------
// Flash attention v13 (round-4 verified): one barrier per KV-tile, STAGE
// after the barrier, swapped-QK^T in-register softmax, ones-MFMA
// denominator, diagonal-tile skip, tile pairing, XCD swizzle. UNCHANGED.
// ---------------------------------------------------------------------------
__global__ __launch_bounds__(512, 4) void flash_attn_k(
    const ushort* __restrict__ Qm, const ushort* __restrict__ Km,
    const ushort* __restrict__ Vt, ushort* __restrict__ Om,
    const int* __restrict__ causal_p)
{
    __shared__ __align__(16) char Ksm[2][16384];   // [buf][kv=64][d=128] bf16
    __shared__ __align__(16) char Vsm[2][16384];   // [buf][d=128][pos=64] bf16

    const int tid = (int)threadIdx.x;
    const int lane = tid & 63, wave = tid >> 6;
    const int fr = lane & 15, fg = lane >> 4;
    const int causal = causal_p[0];

    const int d_raw = (int)blockIdx.x + 8 * ((int)blockIdx.y + 16 * (int)blockIdx.z);
    const int xcd = d_raw & 7, jj = d_raw >> 3;
    const int head_lin = xcd * 8 + (jj & 7);
    const int pi = jj >> 3;                   // 0..7 (pair index)
    const int h = head_lin & 15, b = head_lin >> 4;

    const ushort* Qp = Qm + (size_t)b * TT * CC + h * DD;
    const ushort* Kp = Km + (size_t)b * TT * CC + h * DD;
    const ushort* Vp = Vt + (size_t)(b * HH + h) * DD * TT;
    ushort* Op = Om + (size_t)b * TT * CC + h * DD;

    // all-ones bf16 B-fragment for the row-sum MFMA
    const bh8 onesf = {0x3F80, 0x3F80, 0x3F80, 0x3F80,
                       0x3F80, 0x3F80, 0x3F80, 0x3F80};

    auto STAGE = [&](int ti, int buf) {
        const int kv0 = ti * 64;
        {
            const int r0 = tid >> 4, s0 = tid & 15;
            async16(Kp + (size_t)(kv0 + r0) * CC + (s0 ^ (r0 & 15)) * 8,
                    Ksm[buf] + tid * 16);
            async16(Kp + (size_t)(kv0 + 32 + r0) * CC + (s0 ^ (r0 & 15)) * 8,
                    Ksm[buf] + 8192 + tid * 16);
        }
        {
            const int d0 = tid >> 3, s0 = tid & 7;
            async16(Vp + (size_t)d0 * TT + kv0 + (s0 ^ (d0 & 7)) * 8,
                    Vsm[buf] + tid * 16);
            async16(Vp + (size_t)(64 + d0) * TT + kv0 + (s0 ^ (d0 & 7)) * 8,
                    Vsm[buf] + 8192 + tid * 16);
        }
    };

#pragma unroll 1
    for (int pp = 0; pp < 2; ++pp) {
        const int tile = pp ? (15 - pi) : pi;
        const int q0 = tile * 128;
        const int qbase = q0 + wave * 16;
        const int q_idx = qbase + fr;         // this lane's q-row (swapped layout)

        bh8 qf[4];
#pragma unroll
        for (int s = 0; s < 4; ++s)
            qf[s] = *(const bh8*)&Qp[(size_t)(qbase + fr) * CC + s * 32 + fg * 8];

        fx4 o[8];
#pragma unroll
        for (int jn = 0; jn < 8; ++jn) o[jn] = (fx4){0.f, 0.f, 0.f, 0.f};
        fx4 o_l = (fx4){0.f, 0.f, 0.f, 0.f};

        const int nfull  = causal ? (q0 >> 6) : (TT / 64);
        const int ntiles = causal ? (nfull + 2) : (TT / 64);

        STAGE(0, 0);
#pragma unroll 1
        for (int t = 0; t < ntiles; ++t) {
            // top sync: own loads done -> barrier -> everyone's loads done
            asm volatile("s_waitcnt vmcnt(0)" ::: "memory");
            __builtin_amdgcn_sched_barrier(0);
            __builtin_amdgcn_s_barrier();
            __builtin_amdgcn_sched_barrier(0);
            if (t + 1 < ntiles) STAGE(t + 1, (t + 1) & 1);

            const int kv0 = t * 64;
            const char* kb = Ksm[t & 1];
            const char* vb = Vsm[t & 1];
            const bool domask = causal && (t >= nfull);
            const bool active = !domask || (kv0 <= qbase + 15);

            if (active) {
                // ---- QK^T, swapped: S^T layout; lane holds q=fr, kv=j*16+fg*4+r
                fx4 s4[4];
#pragma unroll
                for (int j = 0; j < 4; ++j) s4[j] = (fx4){0.f, 0.f, 0.f, 0.f};
                __builtin_amdgcn_s_setprio(1);
#pragma unroll
                for (int st = 0; st < 4; ++st) {
                    bh8 kf[4];
#pragma unroll
                    for (int j = 0; j < 4; ++j)
                        kf[j] = *(const bh8*)(kb + (j * 16 + fr) * 256 +
                                              ((st * 64 + fg * 16) ^ (fr << 4)));
#pragma unroll
                    for (int j = 0; j < 4; ++j)
                        s4[j] = __builtin_amdgcn_mfma_f32_16x16x32_bf16(
                            kf[j], qf[st], s4[j], 0, 0, 0);
                }
                __builtin_amdgcn_s_setprio(0);

                // ---- softmax + PV per 32-kv half; P never leaves registers
#pragma unroll
                for (int g = 0; g < 2; ++g) {
                    float pg[2][4];
#pragma unroll
                    for (int j2 = 0; j2 < 2; ++j2) {
                        const int jb = g * 2 + j2;
#pragma unroll
                        for (int r = 0; r < 4; ++r) {
                            float v = s4[jb][r];
                            if (domask && (kv0 + jb * 16 + fg * 4 + r > q_idx))
                                v = -1e30f;
                            pg[j2][r] = exp2f(v);
                        }
                    }
                    // pack to PV A-fragment: k-slot e = jj*4 + r
                    union { uint u[4]; bh8 h; } pk;
                    asm("v_cvt_pk_bf16_f32 %0, %1, %2"
                        : "=v"(pk.u[0]) : "v"(pg[0][0]), "v"(pg[0][1]));
                    asm("v_cvt_pk_bf16_f32 %0, %1, %2"
                        : "=v"(pk.u[1]) : "v"(pg[0][2]), "v"(pg[0][3]));
                    asm("v_cvt_pk_bf16_f32 %0, %1, %2"
                        : "=v"(pk.u[2]) : "v"(pg[1][0]), "v"(pg[1][1]));
                    asm("v_cvt_pk_bf16_f32 %0, %1, %2"
                        : "=v"(pk.u[3]) : "v"(pg[1][2]), "v"(pg[1][3]));
                    const bh8 pf = pk.h;

                    // denominator via matrix pipe: row-sum of this 32-kv half,
                    // D row = fg*4+r (matches epilogue rows), replicated on fr
                    o_l = __builtin_amdgcn_mfma_f32_16x16x32_bf16(
                        pf, onesf, o_l, 0, 0, 0);

                    __builtin_amdgcn_s_setprio(1);
#pragma unroll
                    for (int jn = 0; jn < 8; ++jn) {
                        bh8 vf = *(const bh8*)(vb + (jn * 16 + fr) * 128 +
                                               ((g * 64 + fg * 16) ^ ((fr & 7) << 4)));
                        o[jn] = __builtin_amdgcn_mfma_f32_16x16x32_bf16(
                            pf, vf, o[jn], 0, 0, 0);
                    }
                    __builtin_amdgcn_s_setprio(0);
                }
            }
        }

        // ---- epilogue: l already per-lane in D-layout (no shuffles)
#pragma unroll
        for (int r = 0; r < 4; ++r) {
            const float inv = 1.0f / o_l[r];
            const size_t rowoff = (size_t)(qbase + fg * 4 + r) * CC;
#pragma unroll
            for (int jn = 0; jn < 8; ++jn)
                Op[rowoff + jn * 16 + fr] = f2bf(o[jn][r] * inv);
        }
    }
}

// ---------------------------------------------------------------------------
extern "C" void kernel_launch(void* const* d_in, const int* in_sizes, int n_in,
                              void* d_out, int out_size, void* d_ws, size_t ws_size,
                              hipStream_t stream)
{
    (void)in_sizes; (void)n_in; (void)out_size;
    const float* querys = (const float*)d_in[0];
    const float* keys   = (const float*)d_in[1];
    const float* values = (const float*)d_in[2];
    const float* Wq = (const float*)d_in[3];
    const float* bq = (const float*)d_in[4];
    const float* Wk = (const float*)d_in[5];
    const float* bk = (const float*)d_in[6];
    const float* Wv = (const float*)d_in[7];
    const float* bv = (const float*)d_in[8];
    const float* Wo = (const float*)d_in[9];
    const float* bo = (const float*)d_in[10];
    const int* is_causal = (const int*)d_in[11];

    const size_t WBYTES = (size_t)CC * CC * 2;   // 8 MiB per weight
    const size_t XBYTES = (size_t)MM * CC * 2;   // 32 MiB per activation
    if (ws_size < 4 * WBYTES + 4 * XBYTES) return;  // need 160 MiB

    uint8_t* ws = (uint8_t*)d_ws;
    ushort* WqT = (ushort*)(ws);
    ushort* WkT = (ushort*)(ws + WBYTES);
    ushort* WvT = (ushort*)(ws + 2 * WBYTES);
    ushort* WoT = (ushort*)(ws + 3 * WBYTES);
    uint8_t* act = ws + 4 * WBYTES;
    ushort* Xq = (ushort*)(act);                 // later: Kb
    ushort* Xk = (ushort*)(act + XBYTES);        // later: Vb, then attn-out
    ushort* Xv = (ushort*)(act + 2 * XBYTES);    // later: Vt
    ushort* Qb = (ushort*)(act + 3 * XBYTES);
    ushort* Kb = Xq;
    ushort* Vb = Xk;
    ushort* Vt = Xv;
    ushort* Ob = Xk;   // attn output overwrites Vb (dead after transpose_v)

    dim3 tb(32, 8);
    transpose4_w_k<<<dim3(CC / 32, CC / 32, 4), tb, 0, stream>>>(
        Wq, Wk, Wv, Wo, WqT, WkT, WvT, WoT);

    const int nX = MM * CC;
    convert3_k<<<dim3(nX / 4 / 256, 3), 256, 0, stream>>>(
        querys, keys, values, Xq, Xk, Xv, nX);

    // fused Q/K/V projections: 768 blocks, tails backfill
    gemm_qkv_k<<<dim3((MM / 256) * (CC / 256), 3), 512, 0, stream>>>(
        Xq, Xk, Xv, WqT, WkT, WvT, bq, bk, bv, Qb, Kb, Vb);

    dim3 gvt(DD / 32, TT / 32, BB * HH);
    transpose_v_k<<<gvt, tb, 0, stream>>>(Vb, Vt);

    dim3 ga(8, HH, BB);   // pair index x head x batch, 512 threads
    flash_attn_k<<<ga, 512, 0, stream>>>(Qb, Kb, Vt, Ob, is_causal);

    gemm_o_k<<<dim3((MM / 256) * (CC / 256)), 512, 0, stream>>>(
        Ob, WoT, bo, (float*)d_out);
}

// Round 6
// 445.230 us; speedup vs baseline: 1.1575x; 1.0044x over previous
//
#include <hip/hip_runtime.h>
#include <hip/hip_bf16.h>
#include <stdint.h>

// Problem constants
#define BB 4
#define TT 2048
#define CC 2048
#define HH 16
#define DD 128
#define MM (BB*TT)   // 8192 rows

typedef __attribute__((ext_vector_type(8))) short bh8;   // 8 bf16 (4 VGPRs)
typedef __attribute__((ext_vector_type(4))) float fx4;   // MFMA 16x16 accumulator

__device__ inline ushort f2bf(float x) {
    union { float f; uint32_t u; } c; c.f = x;
    uint32_t lsb = (c.u >> 16) & 1u;
    return (ushort)((c.u + 0x7fffu + lsb) >> 16);
}

__device__ inline void async16(const void* g, void* l) {
    __builtin_amdgcn_global_load_lds(
        (const __attribute__((address_space(1))) uint32_t*)g,
        (__attribute__((address_space(3))) uint32_t*)l, 16, 0, 0);
}

// ---------------------------------------------------------------------------
// Fused fp32 -> bf16 convert for all 3 inputs (blockIdx.y selects tensor)
// ---------------------------------------------------------------------------
__global__ __launch_bounds__(256) void convert3_k(
    const float* __restrict__ i0, const float* __restrict__ i1,
    const float* __restrict__ i2,
    ushort* __restrict__ o0, ushort* __restrict__ o1, ushort* __restrict__ o2,
    int n)
{
    const float* in; ushort* out;
    switch (blockIdx.y) {
        case 0:  in = i0; out = o0; break;
        case 1:  in = i1; out = o1; break;
        default: in = i2; out = o2; break;
    }
    int i = (int)(blockIdx.x * 256 + threadIdx.x) * 4;
    if (i + 3 < n) {
        float4 v = *(const float4*)&in[i];
        ushort4 o;
        o.x = f2bf(v.x); o.y = f2bf(v.y); o.z = f2bf(v.z); o.w = f2bf(v.w);
        *(ushort4*)&out[i] = o;
    }
}

// ---------------------------------------------------------------------------
// Fused weight transpose+convert for all 4 weights (blockIdx.z selects).
// W[k][n] fp32 -> Wt[n][k] bf16 (CC x CC), ushort2 stores.
// ---------------------------------------------------------------------------
__global__ __launch_bounds__(256) void transpose4_w_k(
    const float* __restrict__ w0, const float* __restrict__ w1,
    const float* __restrict__ w2, const float* __restrict__ w3,
    ushort* __restrict__ t0, ushort* __restrict__ t1,
    ushort* __restrict__ t2, ushort* __restrict__ t3)
{
    const float* W; ushort* Wt;
    switch (blockIdx.z) {
        case 0:  W = w0; Wt = t0; break;
        case 1:  W = w1; Wt = t1; break;
        case 2:  W = w2; Wt = t2; break;
        default: W = w3; Wt = t3; break;
    }
    __shared__ __align__(16) ushort tile[32][33];
    const int n0 = blockIdx.x * 32, k0 = blockIdx.y * 32;
    const int tx = threadIdx.x, ty = threadIdx.y;   // (32, 8)
#pragma unroll
    for (int r = 0; r < 32; r += 8)
        tile[ty + r][tx] = f2bf(W[(size_t)(k0 + ty + r) * CC + n0 + tx]);  // [kl][nl]
    __syncthreads();
    const int tid = ty * 32 + tx;
    const int p = tid & 15;        // k-pair index
    const int row = tid >> 4;      // 0..15
#pragma unroll
    for (int rr = 0; rr < 2; ++rr) {
        const int n_row = row + rr * 16;
        ushort2 w2;
        w2.x = tile[2 * p][n_row];
        w2.y = tile[2 * p + 1][n_row];
        *(ushort2*)&Wt[(size_t)(n0 + n_row) * CC + k0 + 2 * p] = w2;
    }
}

// ---------------------------------------------------------------------------
// V transpose per head: V[b,t,h*D+d] bf16 -> Vt[((b*H+h)*D+d)*T + pnew(t)]
// pnew: within each 32-aligned t-block, with t = jj*16 + fg*4 + r:
//   p = fg*8 + jj*4 + r  (PV A-fragment k-slot order of swapped-QK^T softmax)
// ---------------------------------------------------------------------------
__global__ __launch_bounds__(256) void transpose_v_k(
    const ushort* __restrict__ V, ushort* __restrict__ Vt)
{
    __shared__ __align__(16) ushort tile[32][33];
    const int bh = blockIdx.z;
    const int b = bh >> 4, h = bh & 15;
    const int t0 = blockIdx.y * 32, d0 = blockIdx.x * 32;
    const int tx = threadIdx.x, ty = threadIdx.y;   // (32, 8)
    const ushort* Vp = V + (size_t)b * TT * CC + h * DD;
#pragma unroll
    for (int r = 0; r < 32; r += 8)
        tile[ty + r][tx] = Vp[(size_t)(t0 + ty + r) * CC + d0 + tx];  // [t][d]
    __syncthreads();
    ushort* Vtp = Vt + (size_t)bh * DD * TT;
    const int tt = t0 + tx;
    const int pnew = (tt & ~31) | (((tt >> 2) & 3) << 3) | (((tt >> 4) & 1) << 2) | (tt & 3);
#pragma unroll
    for (int r = 0; r < 32; r += 8)
        Vtp[(size_t)(d0 + ty + r) * TT + pnew] = tile[tx][ty + r];
}

// ---------------------------------------------------------------------------
// GEMM v11: register-double-buffered pipeline, ONE barrier per K-tile.
// Round-5 lesson: boundary-sync thinning was worth only 2% -> the stall is
// PHASE SERIALIZATION: per K-tile, LDS reads (192 b128 ~ 2313 cy/CU) and
// MFMA (2483 cy/CU) ran sequentially (util ~ 2483/(2483+2313) = 49%, meas 43).
// v11 makes them concurrent:
//   [vmcnt(0); barrier]  (stage(t) DMAs landed; issued a full tile ago)
//   ds_read set0 (kk0: 4 B + 8 A frags)
//   stage(t+1) all 4 groups (other LDS buffer)
//   ds_read set1 (kk1 frags)
//   MFMA x32 on set0   (lgkm waits only the first 12 reads; set1 reads and
//                       DMA writes proceed under the MFMA cluster)
//   MFMA x32 on set1   (reads long since complete)
// No mid-tile barriers: waves free-run within the tile. Safety: stage(t+1)
// targets the other dbuf; stage(t+2) is issued only after barrier(t+1),
// by which time every wave's reads of buf[t&1] are complete (lgkm-ordered
// before its own MFMAs, which precede its barrier arrival).
// Cost: frag regs x2 (+48 VGPR, ~245 total -- watch 256 cliff).
// ---------------------------------------------------------------------------
template<int OUTF>
__device__ __forceinline__ void gemm_body(
    const ushort* A, const ushort* Bt, const float* bias, void* Cv, float osc)
{
    __shared__ __align__(16) char Gsm[2][65536];  // [dbuf][A.k0|A.k1|B.k0|B.k1]

    const int tid = (int)threadIdx.x;
    const int lane = tid & 63, wave = tid >> 6;
    const int fr = lane & 15, fg = lane >> 4;      // frag row / k-slot group
    const int wm = wave >> 2, wn = wave & 3;       // 2m x 4n wave grid

    // XCD-locality remap: xcd = bid%8 (dispatch round-robin), 32 blocks/XCD
    // cover m_tiles [xcd*4, xcd*4+4) x n_tiles [0,8).
    const int bid = (int)blockIdx.x;
    const int xcd = bid & 7, local = bid >> 3;
    const int m_tile = xcd * 4 + (local >> 3);
    const int n_tile = local & 7;
    const int m0 = m_tile * 256, n0 = n_tile * 256;

    const ushort* Ag = A  + (size_t)m0 * CC;
    const ushort* Bg = Bt + (size_t)n0 * CC;
    const int nt = CC / 64;                        // 32 K-tiles (BK=64)

    // stage group g of tile t: g0=A.k0 g1=B.k0 g2=A.k1 g3=B.k1 (2 loads)
    auto STAGE_G = [&](int t, int g) {
        if (t >= nt) return;
        const int khalf = g >> 1, isB = g & 1;
        char* base = Gsm[t & 1] + isB * 32768 + khalf * 16384;
        const ushort* src = isB ? Bg : Ag;
        const int kbase = t * 64 + khalf * 32;
#pragma unroll
        for (int l = 0; l < 2; ++l) {
            const int u = l * 512 + tid;
            const int j = u >> 3, s = u & 7;
            const int ek = s ^ (j & 7);
            const int e = (ek >> 2) & 1, ks = ek & 3;
            async16(src + (size_t)(2 * j + e) * CC + kbase + ks * 8,
                    base + u * 16);
        }
    };

    // fragment byte offsets within a 16KB region (pair-XOR; +16 rows = +1024)
    const int slot = ((((fr & 1) << 2) | fg) ^ ((fr >> 1) & 7));
    const int offA = (wm * 64 + (fr >> 1)) * 128 + slot * 16;           // +mf*1024
    const int offB = 32768 + (wn * 32 + (fr >> 1)) * 128 + slot * 16;   // +nf*1024

    fx4 acc[8][4];
#pragma unroll
    for (int i = 0; i < 8; ++i)
#pragma unroll
        for (int j = 0; j < 4; ++j)
            acc[i][j] = (fx4){0.f, 0.f, 0.f, 0.f};

    // prologue: tile 0 all 4 groups (8 loads/thread)
#pragma unroll
    for (int g = 0; g < 4; ++g) STAGE_G(0, g);

#pragma unroll 1
    for (int t = 0; t < nt; ++t) {
        const char* kb = Gsm[t & 1];
        const char* ka0 = kb;              // kk0 A region (B via offB +32768)
        const char* ka1 = kb + 16384;      // kk1 regions

        // ---- tile boundary: the ONLY barrier ----
        asm volatile("s_waitcnt vmcnt(0)" ::: "memory");
        __builtin_amdgcn_sched_barrier(0);
        __builtin_amdgcn_s_barrier();
        __builtin_amdgcn_sched_barrier(0);

        bh8 a0[8], b0[4], a1[8], b1[4];

        // set0 reads (kk0)
#pragma unroll
        for (int nf = 0; nf < 4; ++nf)
            b0[nf] = *(const bh8*)(ka0 + offB + nf * 1024);
#pragma unroll
        for (int i = 0; i < 8; ++i)
            a0[i] = *(const bh8*)(ka0 + offA + i * 1024);

        // stage next tile (other dbuf) while reads are in flight
#pragma unroll
        for (int g = 0; g < 4; ++g) STAGE_G(t + 1, g);

        // set1 reads (kk1) -- complete under the kk0 MFMA cluster
#pragma unroll
        for (int nf = 0; nf < 4; ++nf)
            b1[nf] = *(const bh8*)(ka1 + offB + nf * 1024);
#pragma unroll
        for (int i = 0; i < 8; ++i)
            a1[i] = *(const bh8*)(ka1 + offA + i * 1024);

        __builtin_amdgcn_s_setprio(1);
#pragma unroll
        for (int i = 0; i < 8; ++i)
#pragma unroll
            for (int nf = 0; nf < 4; ++nf)
                acc[i][nf] = __builtin_amdgcn_mfma_f32_16x16x32_bf16(
                    a0[i], b0[nf], acc[i][nf], 0, 0, 0);
        __builtin_amdgcn_s_setprio(0);

        __builtin_amdgcn_s_setprio(1);
#pragma unroll
        for (int i = 0; i < 8; ++i)
#pragma unroll
            for (int nf = 0; nf < 4; ++nf)
                acc[i][nf] = __builtin_amdgcn_mfma_f32_16x16x32_bf16(
                    a1[i], b1[nf], acc[i][nf], 0, 0, 0);
        __builtin_amdgcn_s_setprio(0);
    }

    // epilogue: C/D layout col=lane&15, row=(lane>>4)*4+reg
#pragma unroll
    for (int nf = 0; nf < 4; ++nf) {
        const int col = n0 + wn * 64 + nf * 16 + fr;
        const float bv = bias[col];
#pragma unroll
        for (int mf = 0; mf < 8; ++mf) {
            const int row = m0 + wm * 128 + mf * 16 + fg * 4;
#pragma unroll
            for (int r = 0; r < 4; ++r) {
                float v = (acc[mf][nf][r] + bv) * osc;
                if (OUTF)
                    ((float*)Cv)[(size_t)(row + r) * CC + col] = v;
                else
                    ((ushort*)Cv)[(size_t)(row + r) * CC + col] = f2bf(v);
            }
        }
    }
}

// Fused Q/K/V projection GEMM: grid (256, 3), blockIdx.y selects tensor.
__global__ __launch_bounds__(512, 2) void gemm_qkv_k(
    const ushort* __restrict__ Xq, const ushort* __restrict__ Xk,
    const ushort* __restrict__ Xv,
    const ushort* __restrict__ WqT, const ushort* __restrict__ WkT,
    const ushort* __restrict__ WvT,
    const float* __restrict__ bq, const float* __restrict__ bk,
    const float* __restrict__ bv,
    ushort* __restrict__ Qb, ushort* __restrict__ Kb, ushort* __restrict__ Vb)
{
    const ushort* A; const ushort* Bt; const float* bias; ushort* Cv; float osc;
    switch (blockIdx.y) {
        case 0:  A = Xq; Bt = WqT; bias = bq; Cv = Qb;
                 osc = 0.12751789836306614f; break;   // log2(e)/sqrt(128)
        case 1:  A = Xk; Bt = WkT; bias = bk; Cv = Kb; osc = 1.0f; break;
        default: A = Xv; Bt = WvT; bias = bv; Cv = Vb; osc = 1.0f; break;
    }
    gemm_body<0>(A, Bt, bias, Cv, osc);
}

// Output projection GEMM (fp32 out)
__global__ __launch_bounds__(512, 2) void gemm_o_k(
    const ushort* __restrict__ A, const ushort* __restrict__ Bt,
    const float* __restrict__ bias, float* __restrict__ Cv)
{
    gemm_body<1>(A, Bt, bias, Cv, 1.0f);
}

// ---------------------------------------------------------------------------
// Flash attention v13 (round-4 verified): one barrier per KV-tile, STAGE
// after the barrier, swapped-QK^T in-register softmax, ones-MFMA
// denominator, diagonal-tile skip, tile pairing, XCD swizzle. UNCHANGED.
// ---------------------------------------------------------------------------
__global__ __launch_bounds__(512, 4) void flash_attn_k(
    const ushort* __restrict__ Qm, const ushort* __restrict__ Km,
    const ushort* __restrict__ Vt, ushort* __restrict__ Om,
    const int* __restrict__ causal_p)
{
    __shared__ __align__(16) char Ksm[2][16384];   // [buf][kv=64][d=128] bf16
    __shared__ __align__(16) char Vsm[2][16384];   // [buf][d=128][pos=64] bf16

    const int tid = (int)threadIdx.x;
    const int lane = tid & 63, wave = tid >> 6;
    const int fr = lane & 15, fg = lane >> 4;
    const int causal = causal_p[0];

    const int d_raw = (int)blockIdx.x + 8 * ((int)blockIdx.y + 16 * (int)blockIdx.z);
    const int xcd = d_raw & 7, jj = d_raw >> 3;
    const int head_lin = xcd * 8 + (jj & 7);
    const int pi = jj >> 3;                   // 0..7 (pair index)
    const int h = head_lin & 15, b = head_lin >> 4;

    const ushort* Qp = Qm + (size_t)b * TT * CC + h * DD;
    const ushort* Kp = Km + (size_t)b * TT * CC + h * DD;
    const ushort* Vp = Vt + (size_t)(b * HH + h) * DD * TT;
    ushort* Op = Om + (size_t)b * TT * CC + h * DD;

    // all-ones bf16 B-fragment for the row-sum MFMA
    const bh8 onesf = {0x3F80, 0x3F80, 0x3F80, 0x3F80,
                       0x3F80, 0x3F80, 0x3F80, 0x3F80};

    auto STAGE = [&](int ti, int buf) {
        const int kv0 = ti * 64;
        {
            const int r0 = tid >> 4, s0 = tid & 15;
            async16(Kp + (size_t)(kv0 + r0) * CC + (s0 ^ (r0 & 15)) * 8,
                    Ksm[buf] + tid * 16);
            async16(Kp + (size_t)(kv0 + 32 + r0) * CC + (s0 ^ (r0 & 15)) * 8,
                    Ksm[buf] + 8192 + tid * 16);
        }
        {
            const int d0 = tid >> 3, s0 = tid & 7;
            async16(Vp + (size_t)d0 * TT + kv0 + (s0 ^ (d0 & 7)) * 8,
                    Vsm[buf] + tid * 16);
            async16(Vp + (size_t)(64 + d0) * TT + kv0 + (s0 ^ (d0 & 7)) * 8,
                    Vsm[buf] + 8192 + tid * 16);
        }
    };

#pragma unroll 1
    for (int pp = 0; pp < 2; ++pp) {
        const int tile = pp ? (15 - pi) : pi;
        const int q0 = tile * 128;
        const int qbase = q0 + wave * 16;
        const int q_idx = qbase + fr;         // this lane's q-row (swapped layout)

        bh8 qf[4];
#pragma unroll
        for (int s = 0; s < 4; ++s)
            qf[s] = *(const bh8*)&Qp[(size_t)(qbase + fr) * CC + s * 32 + fg * 8];

        fx4 o[8];
#pragma unroll
        for (int jn = 0; jn < 8; ++jn) o[jn] = (fx4){0.f, 0.f, 0.f, 0.f};
        fx4 o_l = (fx4){0.f, 0.f, 0.f, 0.f};

        const int nfull  = causal ? (q0 >> 6) : (TT / 64);
        const int ntiles = causal ? (nfull + 2) : (TT / 64);

        STAGE(0, 0);
#pragma unroll 1
        for (int t = 0; t < ntiles; ++t) {
            // top sync: own loads done -> barrier -> everyone's loads done
            asm volatile("s_waitcnt vmcnt(0)" ::: "memory");
            __builtin_amdgcn_sched_barrier(0);
            __builtin_amdgcn_s_barrier();
            __builtin_amdgcn_sched_barrier(0);
            if (t + 1 < ntiles) STAGE(t + 1, (t + 1) & 1);

            const int kv0 = t * 64;
            const char* kb = Ksm[t & 1];
            const char* vb = Vsm[t & 1];
            const bool domask = causal && (t >= nfull);
            const bool active = !domask || (kv0 <= qbase + 15);

            if (active) {
                // ---- QK^T, swapped: S^T layout; lane holds q=fr, kv=j*16+fg*4+r
                fx4 s4[4];
#pragma unroll
                for (int j = 0; j < 4; ++j) s4[j] = (fx4){0.f, 0.f, 0.f, 0.f};
                __builtin_amdgcn_s_setprio(1);
#pragma unroll
                for (int st = 0; st < 4; ++st) {
                    bh8 kf[4];
#pragma unroll
                    for (int j = 0; j < 4; ++j)
                        kf[j] = *(const bh8*)(kb + (j * 16 + fr) * 256 +
                                              ((st * 64 + fg * 16) ^ (fr << 4)));
#pragma unroll
                    for (int j = 0; j < 4; ++j)
                        s4[j] = __builtin_amdgcn_mfma_f32_16x16x32_bf16(
                            kf[j], qf[st], s4[j], 0, 0, 0);
                }
                __builtin_amdgcn_s_setprio(0);

                // ---- softmax + PV per 32-kv half; P never leaves registers
#pragma unroll
                for (int g = 0; g < 2; ++g) {
                    float pg[2][4];
#pragma unroll
                    for (int j2 = 0; j2 < 2; ++j2) {
                        const int jb = g * 2 + j2;
#pragma unroll
                        for (int r = 0; r < 4; ++r) {
                            float v = s4[jb][r];
                            if (domask && (kv0 + jb * 16 + fg * 4 + r > q_idx))
                                v = -1e30f;
                            pg[j2][r] = exp2f(v);
                        }
                    }
                    // pack to PV A-fragment: k-slot e = jj*4 + r
                    union { uint u[4]; bh8 h; } pk;
                    asm("v_cvt_pk_bf16_f32 %0, %1, %2"
                        : "=v"(pk.u[0]) : "v"(pg[0][0]), "v"(pg[0][1]));
                    asm("v_cvt_pk_bf16_f32 %0, %1, %2"
                        : "=v"(pk.u[1]) : "v"(pg[0][2]), "v"(pg[0][3]));
                    asm("v_cvt_pk_bf16_f32 %0, %1, %2"
                        : "=v"(pk.u[2]) : "v"(pg[1][0]), "v"(pg[1][1]));
                    asm("v_cvt_pk_bf16_f32 %0, %1, %2"
                        : "=v"(pk.u[3]) : "v"(pg[1][2]), "v"(pg[1][3]));
                    const bh8 pf = pk.h;

                    // denominator via matrix pipe: row-sum of this 32-kv half,
                    // D row = fg*4+r (matches epilogue rows), replicated on fr
                    o_l = __builtin_amdgcn_mfma_f32_16x16x32_bf16(
                        pf, onesf, o_l, 0, 0, 0);

                    __builtin_amdgcn_s_setprio(1);
#pragma unroll
                    for (int jn = 0; jn < 8; ++jn) {
                        bh8 vf = *(const bh8*)(vb + (jn * 16 + fr) * 128 +
                                               ((g * 64 + fg * 16) ^ ((fr & 7) << 4)));
                        o[jn] = __builtin_amdgcn_mfma_f32_16x16x32_bf16(
                            pf, vf, o[jn], 0, 0, 0);
                    }
                    __builtin_amdgcn_s_setprio(0);
                }
            }
        }

        // ---- epilogue: l already per-lane in D-layout (no shuffles)
#pragma unroll
        for (int r = 0; r < 4; ++r) {
            const float inv = 1.0f / o_l[r];
            const size_t rowoff = (size_t)(qbase + fg * 4 + r) * CC;
#pragma unroll
            for (int jn = 0; jn < 8; ++jn)
                Op[rowoff + jn * 16 + fr] = f2bf(o[jn][r] * inv);
        }
    }
}

// ---------------------------------------------------------------------------
extern "C" void kernel_launch(void* const* d_in, const int* in_sizes, int n_in,
                              void* d_out, int out_size, void* d_ws, size_t ws_size,
                              hipStream_t stream)
{
    (void)in_sizes; (void)n_in; (void)out_size;
    const float* querys = (const float*)d_in[0];
    const float* keys   = (const float*)d_in[1];
    const float* values = (const float*)d_in[2];
    const float* Wq = (const float*)d_in[3];
    const float* bq = (const float*)d_in[4];
    const float* Wk = (const float*)d_in[5];
    const float* bk = (const float*)d_in[6];
    const float* Wv = (const float*)d_in[7];
    const float* bv = (const float*)d_in[8];
    const float* Wo = (const float*)d_in[9];
    const float* bo = (const float*)d_in[10];
    const int* is_causal = (const int*)d_in[11];

    const size_t WBYTES = (size_t)CC * CC * 2;   // 8 MiB per weight
    const size_t XBYTES = (size_t)MM * CC * 2;   // 32 MiB per activation
    if (ws_size < 4 * WBYTES + 4 * XBYTES) return;  // need 160 MiB

    uint8_t* ws = (uint8_t*)d_ws;
    ushort* WqT = (ushort*)(ws);
    ushort* WkT = (ushort*)(ws + WBYTES);
    ushort* WvT = (ushort*)(ws + 2 * WBYTES);
    ushort* WoT = (ushort*)(ws + 3 * WBYTES);
    uint8_t* act = ws + 4 * WBYTES;
    ushort* Xq = (ushort*)(act);                 // later: Kb
    ushort* Xk = (ushort*)(act + XBYTES);        // later: Vb, then attn-out
    ushort* Xv = (ushort*)(act + 2 * XBYTES);    // later: Vt
    ushort* Qb = (ushort*)(act + 3 * XBYTES);
    ushort* Kb = Xq;
    ushort* Vb = Xk;
    ushort* Vt = Xv;
    ushort* Ob = Xk;   // attn output overwrites Vb (dead after transpose_v)

    dim3 tb(32, 8);
    transpose4_w_k<<<dim3(CC / 32, CC / 32, 4), tb, 0, stream>>>(
        Wq, Wk, Wv, Wo, WqT, WkT, WvT, WoT);

    const int nX = MM * CC;
    convert3_k<<<dim3(nX / 4 / 256, 3), 256, 0, stream>>>(
        querys, keys, values, Xq, Xk, Xv, nX);

    // fused Q/K/V projections: 768 blocks, tails backfill
    gemm_qkv_k<<<dim3((MM / 256) * (CC / 256), 3), 512, 0, stream>>>(
        Xq, Xk, Xv, WqT, WkT, WvT, bq, bk, bv, Qb, Kb, Vb);

    dim3 gvt(DD / 32, TT / 32, BB * HH);
    transpose_v_k<<<gvt, tb, 0, stream>>>(Vb, Vt);

    dim3 ga(8, HH, BB);   // pair index x head x batch, 512 threads
    flash_attn_k<<<ga, 512, 0, stream>>>(Qb, Kb, Vt, Ob, is_causal);

    gemm_o_k<<<dim3((MM / 256) * (CC / 256)), 512, 0, stream>>>(
        Ob, WoT, bo, (float*)d_out);
}